// Round 1
// baseline (1272.823 us; speedup 1.0000x reference)
//
#include <hip/hip_runtime.h>
#include <hip/hip_bf16.h>
#include <cstdint>
#include <cstddef>

#define N_NODES 50000
#define N_EDGES 600000
#define DF 128
#define N_ETYPES 4
#define N_STEPS 5
#define SCAN_NB 196        // ceil(50000/256)
#define GRU_TILES 3125     // 50000/16 exact
#define GRU_BLOCKS 625     // 3125/625 = 5 tiles/block; ~2.4 blocks/CU of work -> 2 resident
#define LSTRIDE 130        // k_gru LDS row stride (floats): 2-way bank alias only (free)
#define TSTRIDE 136        // k_lin LDS tile row stride (f16)

typedef _Float16 f16x8 __attribute__((ext_vector_type(8)));
typedef _Float16 f16x4 __attribute__((ext_vector_type(4)));
typedef _Float16 f16x2 __attribute__((ext_vector_type(2)));
typedef float f32x4 __attribute__((ext_vector_type(4)));

__device__ __forceinline__ float sigmoid_fast(float x) {
    return 1.0f / (1.0f + __expf(-x));
}
__device__ __forceinline__ float tanh_fast(float x) {
    return 1.0f - 2.0f / (__expf(2.0f * x) + 1.0f);
}

// ---------------- setup kernels (once per launch) ----------------

// Wl -> f16; build concatenated GRU B matrix Bc[g*128+c][k]: k<128 -> wih, else whh
__global__ __launch_bounds__(256) void k_cvt_w(
    const float* __restrict__ Wl, const float* __restrict__ wih,
    const float* __restrict__ whh, _Float16* __restrict__ Wl_h,
    _Float16* __restrict__ Bc) {
    int i = blockIdx.x * 256 + threadIdx.x;          // grid covers 98304
    if (i < N_ETYPES * DF * DF) Wl_h[i] = (_Float16)Wl[i];
    int row = i >> 8;                                // 0..383 = g*128 + c
    int k = i & 255;
    float v = (k < 128) ? wih[row * 128 + k] : whh[row * 128 + (k - 128)];
    Bc[i] = (_Float16)v;
}

__global__ __launch_bounds__(256) void k_cvt_h(
    const float* __restrict__ h, _Float16* __restrict__ hh, int n4) {
    int i = blockIdx.x * 256 + threadIdx.x;
    if (i < n4) {
        float4 v = ((const float4*)h)[i];
        f16x4 o;
        o.x = (_Float16)v.x; o.y = (_Float16)v.y;
        o.z = (_Float16)v.z; o.w = (_Float16)v.w;
        ((f16x4*)hh)[i] = o;
    }
}

__global__ __launch_bounds__(256) void k_hist(
    const int* __restrict__ dst, int* __restrict__ deg, int E) {
    int i = blockIdx.x * 256 + threadIdx.x;
    if (i < E) atomicAdd(&deg[dst[i]], 1);
}

// hierarchical exclusive scan over deg[0..N)
__global__ __launch_bounds__(256) void k_part(
    const int* __restrict__ deg, int* __restrict__ part, int N) {
    __shared__ int s[256];
    int t = threadIdx.x, i = blockIdx.x * 256 + t;
    s[t] = (i < N) ? deg[i] : 0;
    __syncthreads();
    for (int off = 128; off > 0; off >>= 1) {
        if (t < off) s[t] += s[t + off];
        __syncthreads();
    }
    if (t == 0) part[blockIdx.x] = s[0];
}

__global__ __launch_bounds__(256) void k_scan1(int* __restrict__ part, int nb) {
    __shared__ int s[256];
    int t = threadIdx.x;
    int v = (t < nb) ? part[t] : 0;
    s[t] = v;
    __syncthreads();
    for (int off = 1; off < 256; off <<= 1) {
        int u = (t >= off) ? s[t - off] : 0;
        __syncthreads();
        s[t] += u;
        __syncthreads();
    }
    if (t < nb) part[t] = s[t] - v;
}

__global__ __launch_bounds__(256) void k_row(
    const int* __restrict__ deg, const int* __restrict__ part,
    int* __restrict__ row_start, int* __restrict__ cursor, int N) {
    __shared__ int s[256];
    int t = threadIdx.x, i = blockIdx.x * 256 + t;
    int d = (i < N) ? deg[i] : 0;
    s[t] = d;
    __syncthreads();
    for (int off = 1; off < 256; off <<= 1) {
        int u = (t >= off) ? s[t - off] : 0;
        __syncthreads();
        s[t] += u;
        __syncthreads();
    }
    int rs = part[blockIdx.x] + s[t] - d;
    if (i < N) {
        row_start[i] = rs;
        cursor[i] = rs;
        if (i == N - 1) row_start[N] = rs + d;
    }
}

__global__ __launch_bounds__(256) void k_fill(
    const int* __restrict__ src, const int* __restrict__ dst,
    const int* __restrict__ ety, int* __restrict__ cursor,
    int* __restrict__ csr, int E) {
    int i = blockIdx.x * 256 + threadIdx.x;
    if (i < E) {
        int slot = atomicAdd(&cursor[dst[i]], 1);
        csr[slot] = src[i] | ((ety[i] - 1) << 16);   // src < 65536, et in 0..3
    }
}

// ---------------- per-step kernels ----------------

// t[k][n][f] = sum_d h[n,d] * W[k][f,d] + b_lin[k][f]   (f16 h in, f16 out)
// One etype per block (grid.y): 4x the waves of the fused version -> latency
// hiding via TLP; per-etype weights (32 KB) go L1-resident per CU.
// Epilogue: wave-private LDS transpose -> contiguous 1KB dwordx4 stores.
__global__ __launch_bounds__(256) void k_lin(
    const _Float16* __restrict__ hh, const _Float16* __restrict__ Wl,
    const float* __restrict__ b_lin, _Float16* __restrict__ t_out, int N) {
    __shared__ _Float16 T[4 * 16 * TSTRIDE];
    const int wave = threadIdx.x >> 6, lane = threadIdx.x & 63;
    const int col = lane & 15, quad = lane >> 4;
    const int r0 = blockIdx.x * 64 + wave * 16;
    const int ktype = blockIdx.y;
    _Float16* Tw = &T[wave * 16 * TSTRIDE];
    int arow = r0 + col; if (arow >= N) arow = N - 1;
    f16x8 a[4];
    const _Float16* hp = hh + (size_t)arow * DF + quad * 8;
#pragma unroll
    for (int kt = 0; kt < 4; kt++) a[kt] = *(const f16x8*)(hp + kt * 32);
    const _Float16* W = Wl + (size_t)ktype * DF * DF;
    _Float16* tk = t_out + (size_t)ktype * N * DF;
    f32x4 accs[8];
#pragma unroll
    for (int ft = 0; ft < 8; ft++) {
        f32x4 acc = {0.f, 0.f, 0.f, 0.f};
        const _Float16* wrow = W + (size_t)(ft * 16 + col) * DF + quad * 8;
#pragma unroll
        for (int kt = 0; kt < 4; kt++)
            acc = __builtin_amdgcn_mfma_f32_16x16x32_f16(
                a[kt], *(const f16x8*)(wrow + kt * 32), acc, 0, 0, 0);
        accs[ft] = acc;
    }
    // C-layout -> wave-private LDS tile (same-wave RAW/WAR: no barrier needed)
#pragma unroll
    for (int ft = 0; ft < 8; ft++) {
        float bias = b_lin[ktype * DF + ft * 16 + col];
#pragma unroll
        for (int i = 0; i < 4; i++)
            Tw[(quad * 4 + i) * TSTRIDE + ft * 16 + col] = (_Float16)(accs[ft][i] + bias);
    }
    // row-major readback: each wave-store = contiguous 1KB (4 rows x 256B).
    // N % 16 == 0, so a wave's 16 rows are all-in or all-out: r0 guard suffices.
    if (r0 < N) {
#pragma unroll
        for (int j = 0; j < 4; j++) {
            int chunk = lane + 64 * j;               // 0..255
            int row = chunk >> 4, c8 = chunk & 15;
            f16x8 v = *(const f16x8*)&Tw[row * TSTRIDE + c8 * 8];
            *(f16x8*)(tk + (size_t)(r0 + row) * DF + c8 * 8) = v;
        }
    }
}

// a[n][:] = sum over incoming edges of t[et][src][:]  -> f16
// wave = 4 edge-slots x 16 lanes; each lane loads f16x8 (16B) = 8 cols.
// 16 edges (4 independent gather instrs) in flight per iteration.
__global__ __launch_bounds__(256) void k_agg(
    const _Float16* __restrict__ t, const int* __restrict__ row_start,
    const int* __restrict__ csr, _Float16* __restrict__ ah, int N) {
    const int wave = threadIdx.x >> 6, lane = threadIdx.x & 63;
    const int g4 = lane >> 4;                        // edge slot 0..3
    const int c8 = lane & 15;                        // col chunk: cols c8*8..+7
    const int n = blockIdx.x * 4 + wave;             // grid = N/4 exactly
    const int beg = row_start[n], end = row_start[n + 1];
    float acc[8] = {0.f, 0.f, 0.f, 0.f, 0.f, 0.f, 0.f, 0.f};
    for (int e = beg; e < end; e += 16) {
        int i0 = e + g4, i1 = e + 4 + g4, i2 = e + 8 + g4, i3 = e + 12 + g4;
        float m0 = (i0 < end) ? 1.0f : 0.0f;
        float m1 = (i1 < end) ? 1.0f : 0.0f;
        float m2 = (i2 < end) ? 1.0f : 0.0f;
        float m3 = (i3 < end) ? 1.0f : 0.0f;
        int j0 = (i0 < end) ? i0 : end - 1;
        int j1 = (i1 < end) ? i1 : end - 1;
        int j2 = (i2 < end) ? i2 : end - 1;
        int j3 = (i3 < end) ? i3 : end - 1;
        int p0 = csr[j0], p1 = csr[j1], p2 = csr[j2], p3 = csr[j3];
        f16x8 x0 = *(const f16x8*)(t + ((((size_t)(p0 >> 16)) * N + (p0 & 0xFFFF)) << 7) + c8 * 8);
        f16x8 x1 = *(const f16x8*)(t + ((((size_t)(p1 >> 16)) * N + (p1 & 0xFFFF)) << 7) + c8 * 8);
        f16x8 x2 = *(const f16x8*)(t + ((((size_t)(p2 >> 16)) * N + (p2 & 0xFFFF)) << 7) + c8 * 8);
        f16x8 x3 = *(const f16x8*)(t + ((((size_t)(p3 >> 16)) * N + (p3 & 0xFFFF)) << 7) + c8 * 8);
#pragma unroll
        for (int j = 0; j < 8; j++) acc[j] += m0 * (float)x0[j];
#pragma unroll
        for (int j = 0; j < 8; j++) acc[j] += m1 * (float)x1[j];
#pragma unroll
        for (int j = 0; j < 8; j++) acc[j] += m2 * (float)x2[j];
#pragma unroll
        for (int j = 0; j < 8; j++) acc[j] += m3 * (float)x3[j];
    }
#pragma unroll
    for (int j = 0; j < 8; j++) {
        acc[j] += __shfl_xor(acc[j], 32, 64);
        acc[j] += __shfl_xor(acc[j], 16, 64);
    }
    if (lane < 16) {
        f16x8 o;
#pragma unroll
        for (int j = 0; j < 8; j++) o[j] = (_Float16)acc[j];
        *(f16x8*)(ah + ((size_t)n << 7) + c8 * 8) = o;
    }
}

// GRU, gate-parallel: one block per 16-row tile computes ALL 384 output cols.
// 12 waves = 3 gates x 4 col-slices; each wave's B-slice (2x8 frags) persistent
// in VGPRs across the grid-stride task loop. A (ah||h f16, K=256) read once per
// block. Gate accs exchanged through LDS; epilogue fuses gates -> f16 h_next
// (fp32 h instead on the final step).
// GRID = 625 (not 256): occupancy was grid-capped at 1 block/CU (30%); two
// resident blocks cover each other's barrier/global-latency stalls.
// __launch_bounds__(768,6) pins VGPR <= 85 so 24 waves/CU actually fit.
__global__ __launch_bounds__(768, 6) void k_gru(
    const _Float16* __restrict__ ah, const _Float16* __restrict__ hh,
    const _Float16* __restrict__ Bc, const float* __restrict__ b_ih,
    const float* __restrict__ b_hh, _Float16* __restrict__ hh_next,
    float* __restrict__ out_f32) {
    __shared__ float X[4 * 16 * LSTRIDE];            // [set r,z,in,hn][row][col]
    const int wave = threadIdx.x >> 6, lane = threadIdx.x & 63;
    const int col16 = lane & 15, quad = lane >> 4;
    const int g = wave >> 2;                         // gate 0..2
    const int s = wave & 3;                          // col-slice of 32

    // persistent B fragments: rows (g*128 + s*32 + ct*16 + col16), k = kt*32+quad*8
    f16x8 b[2][8];
#pragma unroll
    for (int ct = 0; ct < 2; ct++) {
        const _Float16* bp = Bc + (((size_t)(g * 128 + s * 32 + ct * 16 + col16)) << 8) + quad * 8;
#pragma unroll
        for (int kt = 0; kt < 8; kt++) b[ct][kt] = *(const f16x8*)(bp + kt * 32);
    }

    // epilogue biases are tile-invariant: hoist out of the task loop
    float bias_r[3], bias_z[3], bihn[3], bhhn[3];
#pragma unroll
    for (int pazz = 0; pazz < 3; pazz++) {
        int col = (threadIdx.x + pazz * 768) & 127;
        bias_r[pazz] = b_ih[col] + b_hh[col];
        bias_z[pazz] = b_ih[128 + col] + b_hh[128 + col];
        bihn[pazz] = b_ih[256 + col];
        bhhn[pazz] = b_hh[256 + col];
    }

    for (int tile = blockIdx.x; tile < GRU_TILES; tile += GRU_BLOCKS) {
        const int r0 = tile * 16;                    // 50000 = 16*3125: no row guards
        const int arow = r0 + col16;
        f16x8 A[8];                                  // kt<4 = a, kt>=4 = h
        const _Float16* ap = ah + ((size_t)arow << 7) + quad * 8;
        const _Float16* hp = hh + ((size_t)arow << 7) + quad * 8;
#pragma unroll
        for (int kt = 0; kt < 4; kt++) A[kt] = *(const f16x8*)(ap + kt * 32);
#pragma unroll
        for (int kt = 0; kt < 4; kt++) A[4 + kt] = *(const f16x8*)(hp + kt * 32);

        // prefetch h_prev for the epilogue NOW: its ~L2/HBM latency rides under
        // the MFMA chain + LDS exchange + barrier instead of after the barrier.
        float hprev[3];
#pragma unroll
        for (int pazz = 0; pazz < 3; pazz++) {
            int e = threadIdx.x + pazz * 768;
            if (e < 2048)
                hprev[pazz] = (float)hh[((size_t)(r0 + (e >> 7)) << 7) + (e & 127)];
        }

        f32x4 acc[2][2];                             // [khalf-set][ct]; g<2 uses set 0 only
#pragma unroll
        for (int u = 0; u < 2; u++)
#pragma unroll
            for (int ct = 0; ct < 2; ct++) acc[u][ct] = (f32x4){0.f, 0.f, 0.f, 0.f};
#pragma unroll
        for (int kt = 0; kt < 8; kt++) {
            const int set = (g == 2 && kt >= 4) ? 1 : 0;
#pragma unroll
            for (int ct = 0; ct < 2; ct++)
                acc[set][ct] = __builtin_amdgcn_mfma_f32_16x16x32_f16(
                    A[kt], b[ct][kt], acc[set][ct], 0, 0, 0);
        }

        // acc -> LDS exchange
#pragma unroll
        for (int ct = 0; ct < 2; ct++) {
            const int cbase = s * 32 + ct * 16 + col16;
            if (g < 2) {
#pragma unroll
                for (int i = 0; i < 4; i++)
                    X[g * (16 * LSTRIDE) + (quad * 4 + i) * LSTRIDE + cbase] = acc[0][ct][i];
            } else {
#pragma unroll
                for (int i = 0; i < 4; i++) {
                    X[2 * (16 * LSTRIDE) + (quad * 4 + i) * LSTRIDE + cbase] = acc[0][ct][i];
                    X[3 * (16 * LSTRIDE) + (quad * 4 + i) * LSTRIDE + cbase] = acc[1][ct][i];
                }
            }
        }
        __syncthreads();

        // epilogue: 2048 elems over 768 threads
#pragma unroll
        for (int pazz = 0; pazz < 3; pazz++) {
            int e = threadIdx.x + pazz * 768;
            if (e < 2048) {
                int row = e >> 7, col = e & 127;
                float vr = X[0 * (16 * LSTRIDE) + row * LSTRIDE + col];
                float vz = X[1 * (16 * LSTRIDE) + row * LSTRIDE + col];
                float vin = X[2 * (16 * LSTRIDE) + row * LSTRIDE + col];
                float vhn = X[3 * (16 * LSTRIDE) + row * LSTRIDE + col];
                float r = sigmoid_fast(vr + bias_r[pazz]);
                float z = sigmoid_fast(vz + bias_z[pazz]);
                float nn = tanh_fast(vin + bihn[pazz] + r * (vhn + bhhn[pazz]));
                float hv = (1.f - z) * nn + z * hprev[pazz];
                size_t idx = ((size_t)(r0 + row) << 7) + col;
                if (out_f32) out_f32[idx] = hv;      // final step: f16 h_next is dead
                else hh_next[idx] = (_Float16)hv;
            }
        }
        __syncthreads();                             // protect X before next tile's writes
    }
}

// ---------------- launch ----------------

extern "C" void kernel_launch(void* const* d_in, const int* in_sizes, int n_in,
                              void* d_out, int out_size, void* d_ws, size_t ws_size,
                              hipStream_t stream) {
    const float* h0    = (const float*)d_in[0];
    const int*   src   = (const int*)d_in[1];
    const int*   dst   = (const int*)d_in[2];
    const int*   ety   = (const int*)d_in[3];
    const float* W_lin = (const float*)d_in[4];
    const float* b_lin = (const float*)d_in[5];
    const float* w_ih  = (const float*)d_in[6];
    const float* w_hh  = (const float*)d_in[7];
    const float* b_ih  = (const float*)d_in[8];
    const float* b_hh  = (const float*)d_in[9];
    float* hout = (float*)d_out;

    char* p = (char*)d_ws;
    auto alloc = [&](size_t bytes) -> char* {
        char* r = p;
        p += (bytes + 255) & ~(size_t)255;
        return r;
    };
    _Float16* h_a    = (_Float16*)alloc((size_t)N_NODES * DF * 2);
    _Float16* h_b    = (_Float16*)alloc((size_t)N_NODES * DF * 2);
    _Float16* a_half = (_Float16*)alloc((size_t)N_NODES * DF * 2);
    _Float16* t_half = (_Float16*)alloc((size_t)N_ETYPES * N_NODES * DF * 2);
    _Float16* Wl_h   = (_Float16*)alloc((size_t)N_ETYPES * DF * DF * 2);
    _Float16* Bc     = (_Float16*)alloc((size_t)3 * DF * 2 * DF * 2);   // [384][256] f16
    int* deg       = (int*)alloc((size_t)N_NODES * 4);
    int* row_start = (int*)alloc((size_t)(N_NODES + 1) * 4);
    int* cursor    = (int*)alloc((size_t)N_NODES * 4);
    int* csr       = (int*)alloc((size_t)N_EDGES * 4);
    int* part      = (int*)alloc((size_t)SCAN_NB * 4);

    hipMemsetAsync(deg, 0, (size_t)N_NODES * 4, stream);
    k_cvt_w<<<384, 256, 0, stream>>>(W_lin, w_ih, w_hh, Wl_h, Bc);
    k_cvt_h<<<(N_NODES * DF / 4 + 255) / 256, 256, 0, stream>>>(h0, h_a, N_NODES * DF / 4);
    k_hist<<<(N_EDGES + 255) / 256, 256, 0, stream>>>(dst, deg, N_EDGES);
    k_part<<<SCAN_NB, 256, 0, stream>>>(deg, part, N_NODES);
    k_scan1<<<1, 256, 0, stream>>>(part, SCAN_NB);
    k_row<<<SCAN_NB, 256, 0, stream>>>(deg, part, row_start, cursor, N_NODES);
    k_fill<<<(N_EDGES + 255) / 256, 256, 0, stream>>>(src, dst, ety, cursor, csr, N_EDGES);

    _Float16* hc = h_a;
    _Float16* hn = h_b;
    const int nb = (N_NODES + 63) / 64;              // 782
    for (int s = 0; s < N_STEPS; s++) {
        k_lin<<<dim3(nb, N_ETYPES), 256, 0, stream>>>(hc, Wl_h, b_lin, t_half, N_NODES);
        k_agg<<<N_NODES / 4, 256, 0, stream>>>(t_half, row_start, csr, a_half, N_NODES);
        float* of = (s == N_STEPS - 1) ? hout : nullptr;
        k_gru<<<GRU_BLOCKS, 768, 0, stream>>>(a_half, hc, Bc, b_ih, b_hh, hn, of);
        _Float16* tmp = hc; hc = hn; hn = tmp;
    }
}

// Round 2
// 894.529 us; speedup vs baseline: 1.4229x; 1.4229x over previous
//
#include <hip/hip_runtime.h>
#include <hip/hip_bf16.h>
#include <cstdint>
#include <cstddef>

#define N_NODES 50000
#define N_EDGES 600000
#define DF 128
#define N_ETYPES 4
#define N_STEPS 5
#define SCAN_NB 196        // ceil(50000/256)
#define GRU_TILES 3125     // 50000/16 exact
#define GRU_BLOCKS 512     // 2 blocks/CU resident (VGPR=60<=64, LDS 2x33KB); 6-7 tiles/block
#define LSTRIDE 130        // k_gru LDS row stride (floats): 2-way bank alias only (free)
#define TSTRIDE 136        // k_lin LDS tile row stride (f16)

typedef _Float16 f16x8 __attribute__((ext_vector_type(8)));
typedef _Float16 f16x4 __attribute__((ext_vector_type(4)));
typedef _Float16 f16x2 __attribute__((ext_vector_type(2)));
typedef float f32x4 __attribute__((ext_vector_type(4)));

__device__ __forceinline__ float sigmoid_fast(float x) {
    return 1.0f / (1.0f + __expf(-x));
}
__device__ __forceinline__ float tanh_fast(float x) {
    return 1.0f - 2.0f / (__expf(2.0f * x) + 1.0f);
}

// ---------------- setup kernels (once per launch) ----------------

// Wl -> f16; build concatenated GRU B matrix Bc[g*128+c][k]: k<128 -> wih, else whh
__global__ __launch_bounds__(256) void k_cvt_w(
    const float* __restrict__ Wl, const float* __restrict__ wih,
    const float* __restrict__ whh, _Float16* __restrict__ Wl_h,
    _Float16* __restrict__ Bc) {
    int i = blockIdx.x * 256 + threadIdx.x;          // grid covers 98304
    if (i < N_ETYPES * DF * DF) Wl_h[i] = (_Float16)Wl[i];
    int row = i >> 8;                                // 0..383 = g*128 + c
    int k = i & 255;
    float v = (k < 128) ? wih[row * 128 + k] : whh[row * 128 + (k - 128)];
    Bc[i] = (_Float16)v;
}

__global__ __launch_bounds__(256) void k_cvt_h(
    const float* __restrict__ h, _Float16* __restrict__ hh, int n4) {
    int i = blockIdx.x * 256 + threadIdx.x;
    if (i < n4) {
        float4 v = ((const float4*)h)[i];
        f16x4 o;
        o.x = (_Float16)v.x; o.y = (_Float16)v.y;
        o.z = (_Float16)v.z; o.w = (_Float16)v.w;
        ((f16x4*)hh)[i] = o;
    }
}

__global__ __launch_bounds__(256) void k_hist(
    const int* __restrict__ dst, int* __restrict__ deg, int E) {
    int i = blockIdx.x * 256 + threadIdx.x;
    if (i < E) atomicAdd(&deg[dst[i]], 1);
}

// hierarchical exclusive scan over deg[0..N)
__global__ __launch_bounds__(256) void k_part(
    const int* __restrict__ deg, int* __restrict__ part, int N) {
    __shared__ int s[256];
    int t = threadIdx.x, i = blockIdx.x * 256 + t;
    s[t] = (i < N) ? deg[i] : 0;
    __syncthreads();
    for (int off = 128; off > 0; off >>= 1) {
        if (t < off) s[t] += s[t + off];
        __syncthreads();
    }
    if (t == 0) part[blockIdx.x] = s[0];
}

__global__ __launch_bounds__(256) void k_scan1(int* __restrict__ part, int nb) {
    __shared__ int s[256];
    int t = threadIdx.x;
    int v = (t < nb) ? part[t] : 0;
    s[t] = v;
    __syncthreads();
    for (int off = 1; off < 256; off <<= 1) {
        int u = (t >= off) ? s[t - off] : 0;
        __syncthreads();
        s[t] += u;
        __syncthreads();
    }
    if (t < nb) part[t] = s[t] - v;
}

__global__ __launch_bounds__(256) void k_row(
    const int* __restrict__ deg, const int* __restrict__ part,
    int* __restrict__ row_start, int* __restrict__ cursor, int N) {
    __shared__ int s[256];
    int t = threadIdx.x, i = blockIdx.x * 256 + t;
    int d = (i < N) ? deg[i] : 0;
    s[t] = d;
    __syncthreads();
    for (int off = 1; off < 256; off <<= 1) {
        int u = (t >= off) ? s[t - off] : 0;
        __syncthreads();
        s[t] += u;
        __syncthreads();
    }
    int rs = part[blockIdx.x] + s[t] - d;
    if (i < N) {
        row_start[i] = rs;
        cursor[i] = rs;
        if (i == N - 1) row_start[N] = rs + d;
    }
}

__global__ __launch_bounds__(256) void k_fill(
    const int* __restrict__ src, const int* __restrict__ dst,
    const int* __restrict__ ety, int* __restrict__ cursor,
    int* __restrict__ csr, int E) {
    int i = blockIdx.x * 256 + threadIdx.x;
    if (i < E) {
        int slot = atomicAdd(&cursor[dst[i]], 1);
        csr[slot] = src[i] | ((ety[i] - 1) << 16);   // src < 65536, et in 0..3
    }
}

// ---------------- per-step kernels ----------------

// t[k][n][f] = sum_d h[n,d] * W[k][f,d] + b_lin[k][f]   (f16 h in, f16 out)
// One etype per block (grid.y): 4x the waves of the fused version -> latency
// hiding via TLP; per-etype weights (32 KB) go L1-resident per CU.
// Epilogue: wave-private LDS transpose -> contiguous 1KB dwordx4 stores.
__global__ __launch_bounds__(256) void k_lin(
    const _Float16* __restrict__ hh, const _Float16* __restrict__ Wl,
    const float* __restrict__ b_lin, _Float16* __restrict__ t_out, int N) {
    __shared__ _Float16 T[4 * 16 * TSTRIDE];
    const int wave = threadIdx.x >> 6, lane = threadIdx.x & 63;
    const int col = lane & 15, quad = lane >> 4;
    const int r0 = blockIdx.x * 64 + wave * 16;
    const int ktype = blockIdx.y;
    _Float16* Tw = &T[wave * 16 * TSTRIDE];
    int arow = r0 + col; if (arow >= N) arow = N - 1;
    f16x8 a[4];
    const _Float16* hp = hh + (size_t)arow * DF + quad * 8;
#pragma unroll
    for (int kt = 0; kt < 4; kt++) a[kt] = *(const f16x8*)(hp + kt * 32);
    const _Float16* W = Wl + (size_t)ktype * DF * DF;
    _Float16* tk = t_out + (size_t)ktype * N * DF;
    f32x4 accs[8];
#pragma unroll
    for (int ft = 0; ft < 8; ft++) {
        f32x4 acc = {0.f, 0.f, 0.f, 0.f};
        const _Float16* wrow = W + (size_t)(ft * 16 + col) * DF + quad * 8;
#pragma unroll
        for (int kt = 0; kt < 4; kt++)
            acc = __builtin_amdgcn_mfma_f32_16x16x32_f16(
                a[kt], *(const f16x8*)(wrow + kt * 32), acc, 0, 0, 0);
        accs[ft] = acc;
    }
    // C-layout -> wave-private LDS tile (same-wave RAW/WAR: no barrier needed)
#pragma unroll
    for (int ft = 0; ft < 8; ft++) {
        float bias = b_lin[ktype * DF + ft * 16 + col];
#pragma unroll
        for (int i = 0; i < 4; i++)
            Tw[(quad * 4 + i) * TSTRIDE + ft * 16 + col] = (_Float16)(accs[ft][i] + bias);
    }
    // row-major readback: each wave-store = contiguous 1KB (4 rows x 256B).
    // N % 16 == 0, so a wave's 16 rows are all-in or all-out: r0 guard suffices.
    if (r0 < N) {
#pragma unroll
        for (int j = 0; j < 4; j++) {
            int chunk = lane + 64 * j;               // 0..255
            int row = chunk >> 4, c8 = chunk & 15;
            f16x8 v = *(const f16x8*)&Tw[row * TSTRIDE + c8 * 8];
            *(f16x8*)(tk + (size_t)(r0 + row) * DF + c8 * 8) = v;
        }
    }
}

// a[n][:] = sum over incoming edges of t[et][src][:]  -> f16
// wave = 4 edge-slots x 16 lanes; each lane loads f16x8 (16B) = 8 cols.
// 16 edges (4 independent gather instrs) in flight per iteration.
__global__ __launch_bounds__(256) void k_agg(
    const _Float16* __restrict__ t, const int* __restrict__ row_start,
    const int* __restrict__ csr, _Float16* __restrict__ ah, int N) {
    const int wave = threadIdx.x >> 6, lane = threadIdx.x & 63;
    const int g4 = lane >> 4;                        // edge slot 0..3
    const int c8 = lane & 15;                        // col chunk: cols c8*8..+7
    const int n = blockIdx.x * 4 + wave;             // grid = N/4 exactly
    const int beg = row_start[n], end = row_start[n + 1];
    float acc[8] = {0.f, 0.f, 0.f, 0.f, 0.f, 0.f, 0.f, 0.f};
    for (int e = beg; e < end; e += 16) {
        int i0 = e + g4, i1 = e + 4 + g4, i2 = e + 8 + g4, i3 = e + 12 + g4;
        float m0 = (i0 < end) ? 1.0f : 0.0f;
        float m1 = (i1 < end) ? 1.0f : 0.0f;
        float m2 = (i2 < end) ? 1.0f : 0.0f;
        float m3 = (i3 < end) ? 1.0f : 0.0f;
        int j0 = (i0 < end) ? i0 : end - 1;
        int j1 = (i1 < end) ? i1 : end - 1;
        int j2 = (i2 < end) ? i2 : end - 1;
        int j3 = (i3 < end) ? i3 : end - 1;
        int p0 = csr[j0], p1 = csr[j1], p2 = csr[j2], p3 = csr[j3];
        f16x8 x0 = *(const f16x8*)(t + ((((size_t)(p0 >> 16)) * N + (p0 & 0xFFFF)) << 7) + c8 * 8);
        f16x8 x1 = *(const f16x8*)(t + ((((size_t)(p1 >> 16)) * N + (p1 & 0xFFFF)) << 7) + c8 * 8);
        f16x8 x2 = *(const f16x8*)(t + ((((size_t)(p2 >> 16)) * N + (p2 & 0xFFFF)) << 7) + c8 * 8);
        f16x8 x3 = *(const f16x8*)(t + ((((size_t)(p3 >> 16)) * N + (p3 & 0xFFFF)) << 7) + c8 * 8);
#pragma unroll
        for (int j = 0; j < 8; j++) acc[j] += m0 * (float)x0[j];
#pragma unroll
        for (int j = 0; j < 8; j++) acc[j] += m1 * (float)x1[j];
#pragma unroll
        for (int j = 0; j < 8; j++) acc[j] += m2 * (float)x2[j];
#pragma unroll
        for (int j = 0; j < 8; j++) acc[j] += m3 * (float)x3[j];
    }
#pragma unroll
    for (int j = 0; j < 8; j++) {
        acc[j] += __shfl_xor(acc[j], 32, 64);
        acc[j] += __shfl_xor(acc[j], 16, 64);
    }
    if (lane < 16) {
        f16x8 o;
#pragma unroll
        for (int j = 0; j < 8; j++) o[j] = (_Float16)acc[j];
        *(f16x8*)(ah + ((size_t)n << 7) + c8 * 8) = o;
    }
}

// GRU, gate-parallel: one block per 16-row tile computes ALL 384 output cols.
// 12 waves = 3 gates x 4 col-slices; each wave's B-slice (2x8 frags) persistent
// in VGPRs across the grid-stride task loop. A (ah||h f16, K=256) read once per
// block. Gate accs exchanged through LDS; epilogue fuses gates -> f16 h_next
// (+ fp32 h on the final step).
// Body is the verified VGPR=60 version — NO launch-bounds coercion (round-1's
// __launch_bounds__(768,6) forced VGPR=40 -> scratch spills -> 224MB FETCH).
// Occupancy comes purely from the grid: 512 blocks = 2 resident/CU
// (12+12=24 waves <= 32, LDS 2x33KB <= 160KB, VGPR 60 <= 64-per-8-wave cap).
__global__ __launch_bounds__(768) void k_gru(
    const _Float16* __restrict__ ah, const _Float16* __restrict__ hh,
    const _Float16* __restrict__ Bc, const float* __restrict__ b_ih,
    const float* __restrict__ b_hh, _Float16* __restrict__ hh_next,
    float* __restrict__ out_f32) {
    __shared__ float X[4 * 16 * LSTRIDE];            // [set r,z,in,hn][row][col]
    const int wave = threadIdx.x >> 6, lane = threadIdx.x & 63;
    const int col16 = lane & 15, quad = lane >> 4;
    const int g = wave >> 2;                         // gate 0..2
    const int s = wave & 3;                          // col-slice of 32

    // persistent B fragments: rows (g*128 + s*32 + ct*16 + col16), k = kt*32+quad*8
    f16x8 b[2][8];
#pragma unroll
    for (int ct = 0; ct < 2; ct++) {
        const _Float16* bp = Bc + (((size_t)(g * 128 + s * 32 + ct * 16 + col16)) << 8) + quad * 8;
#pragma unroll
        for (int kt = 0; kt < 8; kt++) b[ct][kt] = *(const f16x8*)(bp + kt * 32);
    }

    for (int tile = blockIdx.x; tile < GRU_TILES; tile += GRU_BLOCKS) {
        const int r0 = tile * 16;                    // 50000 = 16*3125: no row guards
        const int arow = r0 + col16;
        f16x8 A[8];                                  // kt<4 = a, kt>=4 = h
        const _Float16* ap = ah + ((size_t)arow << 7) + quad * 8;
        const _Float16* hp = hh + ((size_t)arow << 7) + quad * 8;
#pragma unroll
        for (int kt = 0; kt < 4; kt++) A[kt] = *(const f16x8*)(ap + kt * 32);
#pragma unroll
        for (int kt = 0; kt < 4; kt++) A[4 + kt] = *(const f16x8*)(hp + kt * 32);

        f32x4 acc[2][2];                             // [khalf-set][ct]; g<2 uses set 0 only
#pragma unroll
        for (int u = 0; u < 2; u++)
#pragma unroll
            for (int ct = 0; ct < 2; ct++) acc[u][ct] = (f32x4){0.f, 0.f, 0.f, 0.f};
#pragma unroll
        for (int kt = 0; kt < 8; kt++) {
            const int set = (g == 2 && kt >= 4) ? 1 : 0;
#pragma unroll
            for (int ct = 0; ct < 2; ct++)
                acc[set][ct] = __builtin_amdgcn_mfma_f32_16x16x32_f16(
                    A[kt], b[ct][kt], acc[set][ct], 0, 0, 0);
        }

        // acc -> LDS exchange
#pragma unroll
        for (int ct = 0; ct < 2; ct++) {
            const int cbase = s * 32 + ct * 16 + col16;
            if (g < 2) {
#pragma unroll
                for (int i = 0; i < 4; i++)
                    X[g * (16 * LSTRIDE) + (quad * 4 + i) * LSTRIDE + cbase] = acc[0][ct][i];
            } else {
#pragma unroll
                for (int i = 0; i < 4; i++) {
                    X[2 * (16 * LSTRIDE) + (quad * 4 + i) * LSTRIDE + cbase] = acc[0][ct][i];
                    X[3 * (16 * LSTRIDE) + (quad * 4 + i) * LSTRIDE + cbase] = acc[1][ct][i];
                }
            }
        }
        __syncthreads();

        // epilogue: 2048 elems over 768 threads
#pragma unroll
        for (int pazz = 0; pazz < 3; pazz++) {
            int e = threadIdx.x + pazz * 768;
            if (e < 2048) {
                int row = e >> 7, col = e & 127;
                float vr = X[0 * (16 * LSTRIDE) + row * LSTRIDE + col];
                float vz = X[1 * (16 * LSTRIDE) + row * LSTRIDE + col];
                float vin = X[2 * (16 * LSTRIDE) + row * LSTRIDE + col];
                float vhn = X[3 * (16 * LSTRIDE) + row * LSTRIDE + col];
                float r = sigmoid_fast(vr + b_ih[col] + b_hh[col]);
                float z = sigmoid_fast(vz + b_ih[128 + col] + b_hh[128 + col]);
                float nn = tanh_fast(vin + b_ih[256 + col] + r * (vhn + b_hh[256 + col]));
                size_t idx = ((size_t)(r0 + row) << 7) + col;
                float hprev = (float)hh[idx];
                float hv = (1.f - z) * nn + z * hprev;
                hh_next[idx] = (_Float16)hv;
                if (out_f32) out_f32[idx] = hv;
            }
        }
        __syncthreads();                             // protect X before next tile's writes
    }
}

// ---------------- launch ----------------

extern "C" void kernel_launch(void* const* d_in, const int* in_sizes, int n_in,
                              void* d_out, int out_size, void* d_ws, size_t ws_size,
                              hipStream_t stream) {
    const float* h0    = (const float*)d_in[0];
    const int*   src   = (const int*)d_in[1];
    const int*   dst   = (const int*)d_in[2];
    const int*   ety   = (const int*)d_in[3];
    const float* W_lin = (const float*)d_in[4];
    const float* b_lin = (const float*)d_in[5];
    const float* w_ih  = (const float*)d_in[6];
    const float* w_hh  = (const float*)d_in[7];
    const float* b_ih  = (const float*)d_in[8];
    const float* b_hh  = (const float*)d_in[9];
    float* hout = (float*)d_out;

    char* p = (char*)d_ws;
    auto alloc = [&](size_t bytes) -> char* {
        char* r = p;
        p += (bytes + 255) & ~(size_t)255;
        return r;
    };
    _Float16* h_a    = (_Float16*)alloc((size_t)N_NODES * DF * 2);
    _Float16* h_b    = (_Float16*)alloc((size_t)N_NODES * DF * 2);
    _Float16* a_half = (_Float16*)alloc((size_t)N_NODES * DF * 2);
    _Float16* t_half = (_Float16*)alloc((size_t)N_ETYPES * N_NODES * DF * 2);
    _Float16* Wl_h   = (_Float16*)alloc((size_t)N_ETYPES * DF * DF * 2);
    _Float16* Bc     = (_Float16*)alloc((size_t)3 * DF * 2 * DF * 2);   // [384][256] f16
    int* deg       = (int*)alloc((size_t)N_NODES * 4);
    int* row_start = (int*)alloc((size_t)(N_NODES + 1) * 4);
    int* cursor    = (int*)alloc((size_t)N_NODES * 4);
    int* csr       = (int*)alloc((size_t)N_EDGES * 4);
    int* part      = (int*)alloc((size_t)SCAN_NB * 4);

    hipMemsetAsync(deg, 0, (size_t)N_NODES * 4, stream);
    k_cvt_w<<<384, 256, 0, stream>>>(W_lin, w_ih, w_hh, Wl_h, Bc);
    k_cvt_h<<<(N_NODES * DF / 4 + 255) / 256, 256, 0, stream>>>(h0, h_a, N_NODES * DF / 4);
    k_hist<<<(N_EDGES + 255) / 256, 256, 0, stream>>>(dst, deg, N_EDGES);
    k_part<<<SCAN_NB, 256, 0, stream>>>(deg, part, N_NODES);
    k_scan1<<<1, 256, 0, stream>>>(part, SCAN_NB);
    k_row<<<SCAN_NB, 256, 0, stream>>>(deg, part, row_start, cursor, N_NODES);
    k_fill<<<(N_EDGES + 255) / 256, 256, 0, stream>>>(src, dst, ety, cursor, csr, N_EDGES);

    _Float16* hc = h_a;
    _Float16* hn = h_b;
    const int nb = (N_NODES + 63) / 64;              // 782
    for (int s = 0; s < N_STEPS; s++) {
        k_lin<<<dim3(nb, N_ETYPES), 256, 0, stream>>>(hc, Wl_h, b_lin, t_half, N_NODES);
        k_agg<<<N_NODES / 4, 256, 0, stream>>>(t_half, row_start, csr, a_half, N_NODES);
        float* of = (s == N_STEPS - 1) ? hout : nullptr;
        k_gru<<<GRU_BLOCKS, 768, 0, stream>>>(a_half, hc, Bc, b_ih, b_hh, hn, of);
        _Float16* tmp = hc; hc = hn; hn = tmp;
    }
}

// Round 3
// 724.656 us; speedup vs baseline: 1.7565x; 1.2344x over previous
//
#include <hip/hip_runtime.h>
#include <hip/hip_bf16.h>
#include <cstdint>
#include <cstddef>

#define N_NODES 50000
#define N_EDGES 600000
#define DF 128
#define N_ETYPES 4
#define N_STEPS 5
#define SCAN_NB 196        // ceil(50000/256)
#define GRU_TILES 3125     // 50000/16 exact
#define GRU_BLOCKS 256     // 1 block/CU (2-block residency impossible: ~140 regs/wave incl AGPR)
#define LSTRIDE 130        // k_gru LDS row stride (floats): 2-way bank alias only (free)
#define TSTRIDE 136        // k_lin LDS tile row stride (f16)

typedef _Float16 f16x8 __attribute__((ext_vector_type(8)));
typedef _Float16 f16x4 __attribute__((ext_vector_type(4)));
typedef _Float16 f16x2 __attribute__((ext_vector_type(2)));
typedef float f32x4 __attribute__((ext_vector_type(4)));

__device__ __forceinline__ float sigmoid_fast(float x) {
    return 1.0f / (1.0f + __expf(-x));
}
__device__ __forceinline__ float tanh_fast(float x) {
    return 1.0f - 2.0f / (__expf(2.0f * x) + 1.0f);
}

// ---------------- setup kernels (once per launch) ----------------

// Wl -> f16; build concatenated GRU B matrix Bc[g*128+c][k]: k<128 -> wih, else whh
__global__ __launch_bounds__(256) void k_cvt_w(
    const float* __restrict__ Wl, const float* __restrict__ wih,
    const float* __restrict__ whh, _Float16* __restrict__ Wl_h,
    _Float16* __restrict__ Bc) {
    int i = blockIdx.x * 256 + threadIdx.x;          // grid covers 98304
    if (i < N_ETYPES * DF * DF) Wl_h[i] = (_Float16)Wl[i];
    int row = i >> 8;                                // 0..383 = g*128 + c
    int k = i & 255;
    float v = (k < 128) ? wih[row * 128 + k] : whh[row * 128 + (k - 128)];
    Bc[i] = (_Float16)v;
}

__global__ __launch_bounds__(256) void k_cvt_h(
    const float* __restrict__ h, _Float16* __restrict__ hh, int n4) {
    int i = blockIdx.x * 256 + threadIdx.x;
    if (i < n4) {
        float4 v = ((const float4*)h)[i];
        f16x4 o;
        o.x = (_Float16)v.x; o.y = (_Float16)v.y;
        o.z = (_Float16)v.z; o.w = (_Float16)v.w;
        ((f16x4*)hh)[i] = o;
    }
}

__global__ __launch_bounds__(256) void k_hist(
    const int* __restrict__ dst, int* __restrict__ deg, int E) {
    int i = blockIdx.x * 256 + threadIdx.x;
    if (i < E) atomicAdd(&deg[dst[i]], 1);
}

// hierarchical exclusive scan over deg[0..N)
__global__ __launch_bounds__(256) void k_part(
    const int* __restrict__ deg, int* __restrict__ part, int N) {
    __shared__ int s[256];
    int t = threadIdx.x, i = blockIdx.x * 256 + t;
    s[t] = (i < N) ? deg[i] : 0;
    __syncthreads();
    for (int off = 128; off > 0; off >>= 1) {
        if (t < off) s[t] += s[t + off];
        __syncthreads();
    }
    if (t == 0) part[blockIdx.x] = s[0];
}

__global__ __launch_bounds__(256) void k_scan1(int* __restrict__ part, int nb) {
    __shared__ int s[256];
    int t = threadIdx.x;
    int v = (t < nb) ? part[t] : 0;
    s[t] = v;
    __syncthreads();
    for (int off = 1; off < 256; off <<= 1) {
        int u = (t >= off) ? s[t - off] : 0;
        __syncthreads();
        s[t] += u;
        __syncthreads();
    }
    if (t < nb) part[t] = s[t] - v;
}

__global__ __launch_bounds__(256) void k_row(
    const int* __restrict__ deg, const int* __restrict__ part,
    int* __restrict__ row_start, int* __restrict__ cursor, int N) {
    __shared__ int s[256];
    int t = threadIdx.x, i = blockIdx.x * 256 + t;
    int d = (i < N) ? deg[i] : 0;
    s[t] = d;
    __syncthreads();
    for (int off = 1; off < 256; off <<= 1) {
        int u = (t >= off) ? s[t - off] : 0;
        __syncthreads();
        s[t] += u;
        __syncthreads();
    }
    int rs = part[blockIdx.x] + s[t] - d;
    if (i < N) {
        row_start[i] = rs;
        cursor[i] = rs;
        if (i == N - 1) row_start[N] = rs + d;
    }
}

__global__ __launch_bounds__(256) void k_fill(
    const int* __restrict__ src, const int* __restrict__ dst,
    const int* __restrict__ ety, int* __restrict__ cursor,
    int* __restrict__ csr, int E) {
    int i = blockIdx.x * 256 + threadIdx.x;
    if (i < E) {
        int slot = atomicAdd(&cursor[dst[i]], 1);
        csr[slot] = src[i] | ((ety[i] - 1) << 16);   // src < 65536, et in 0..3
    }
}

// ---------------- per-step kernels ----------------

// t[k][n][f] = sum_d h[n,d] * W[k][f,d] + b_lin[k][f]   (f16 h in, f16 out)
__global__ __launch_bounds__(256) void k_lin(
    const _Float16* __restrict__ hh, const _Float16* __restrict__ Wl,
    const float* __restrict__ b_lin, _Float16* __restrict__ t_out, int N) {
    __shared__ _Float16 T[4 * 16 * TSTRIDE];
    const int wave = threadIdx.x >> 6, lane = threadIdx.x & 63;
    const int col = lane & 15, quad = lane >> 4;
    const int r0 = blockIdx.x * 64 + wave * 16;
    const int ktype = blockIdx.y;
    _Float16* Tw = &T[wave * 16 * TSTRIDE];
    int arow = r0 + col; if (arow >= N) arow = N - 1;
    f16x8 a[4];
    const _Float16* hp = hh + (size_t)arow * DF + quad * 8;
#pragma unroll
    for (int kt = 0; kt < 4; kt++) a[kt] = *(const f16x8*)(hp + kt * 32);
    const _Float16* W = Wl + (size_t)ktype * DF * DF;
    _Float16* tk = t_out + (size_t)ktype * N * DF;
    f32x4 accs[8];
#pragma unroll
    for (int ft = 0; ft < 8; ft++) {
        f32x4 acc = {0.f, 0.f, 0.f, 0.f};
        const _Float16* wrow = W + (size_t)(ft * 16 + col) * DF + quad * 8;
#pragma unroll
        for (int kt = 0; kt < 4; kt++)
            acc = __builtin_amdgcn_mfma_f32_16x16x32_f16(
                a[kt], *(const f16x8*)(wrow + kt * 32), acc, 0, 0, 0);
        accs[ft] = acc;
    }
#pragma unroll
    for (int ft = 0; ft < 8; ft++) {
        float bias = b_lin[ktype * DF + ft * 16 + col];
#pragma unroll
        for (int i = 0; i < 4; i++)
            Tw[(quad * 4 + i) * TSTRIDE + ft * 16 + col] = (_Float16)(accs[ft][i] + bias);
    }
    if (r0 < N) {
#pragma unroll
        for (int j = 0; j < 4; j++) {
            int chunk = lane + 64 * j;               // 0..255
            int row = chunk >> 4, c8 = chunk & 15;
            f16x8 v = *(const f16x8*)&Tw[row * TSTRIDE + c8 * 8];
            *(f16x8*)(tk + (size_t)(r0 + row) * DF + c8 * 8) = v;
        }
    }
}

// a[n][:] = sum over incoming edges of t[et][src][:]  -> f16
__global__ __launch_bounds__(256) void k_agg(
    const _Float16* __restrict__ t, const int* __restrict__ row_start,
    const int* __restrict__ csr, _Float16* __restrict__ ah, int N) {
    const int wave = threadIdx.x >> 6, lane = threadIdx.x & 63;
    const int g4 = lane >> 4;                        // edge slot 0..3
    const int c8 = lane & 15;                        // col chunk: cols c8*8..+7
    const int n = blockIdx.x * 4 + wave;             // grid = N/4 exactly
    const int beg = row_start[n], end = row_start[n + 1];
    float acc[8] = {0.f, 0.f, 0.f, 0.f, 0.f, 0.f, 0.f, 0.f};
    for (int e = beg; e < end; e += 16) {
        int i0 = e + g4, i1 = e + 4 + g4, i2 = e + 8 + g4, i3 = e + 12 + g4;
        float m0 = (i0 < end) ? 1.0f : 0.0f;
        float m1 = (i1 < end) ? 1.0f : 0.0f;
        float m2 = (i2 < end) ? 1.0f : 0.0f;
        float m3 = (i3 < end) ? 1.0f : 0.0f;
        int j0 = (i0 < end) ? i0 : end - 1;
        int j1 = (i1 < end) ? i1 : end - 1;
        int j2 = (i2 < end) ? i2 : end - 1;
        int j3 = (i3 < end) ? i3 : end - 1;
        int p0 = csr[j0], p1 = csr[j1], p2 = csr[j2], p3 = csr[j3];
        f16x8 x0 = *(const f16x8*)(t + ((((size_t)(p0 >> 16)) * N + (p0 & 0xFFFF)) << 7) + c8 * 8);
        f16x8 x1 = *(const f16x8*)(t + ((((size_t)(p1 >> 16)) * N + (p1 & 0xFFFF)) << 7) + c8 * 8);
        f16x8 x2 = *(const f16x8*)(t + ((((size_t)(p2 >> 16)) * N + (p2 & 0xFFFF)) << 7) + c8 * 8);
        f16x8 x3 = *(const f16x8*)(t + ((((size_t)(p3 >> 16)) * N + (p3 & 0xFFFF)) << 7) + c8 * 8);
#pragma unroll
        for (int j = 0; j < 8; j++) acc[j] += m0 * (float)x0[j];
#pragma unroll
        for (int j = 0; j < 8; j++) acc[j] += m1 * (float)x1[j];
#pragma unroll
        for (int j = 0; j < 8; j++) acc[j] += m2 * (float)x2[j];
#pragma unroll
        for (int j = 0; j < 8; j++) acc[j] += m3 * (float)x3[j];
    }
#pragma unroll
    for (int j = 0; j < 8; j++) {
        acc[j] += __shfl_xor(acc[j], 32, 64);
        acc[j] += __shfl_xor(acc[j], 16, 64);
    }
    if (lane < 16) {
        f16x8 o;
#pragma unroll
        for (int j = 0; j < 8; j++) o[j] = (_Float16)acc[j];
        *(f16x8*)(ah + ((size_t)n << 7) + c8 * 8) = o;
    }
}

// GRU, gate-parallel, software-pipelined.
// 12 waves = 3 gates x 4 col-slices, B-slices persistent in regs (as before).
// NEW: A-tile (ah||hh, 8KB) staged into a 4-slot LDS ring via global_load_lds,
// issued 2 tiles ahead (waves 0-7, one 1KB dwordx4 each). XOR-swizzled via
// pre-swizzled SOURCE address (LDS dest must stay linear). One counted-vmcnt
// barrier per tile (s_waitcnt vmcnt(1), never 0: prefetch stays in flight).
// X double-buffered -> second barrier removed. hprev read from staged hh in
// LDS -> epilogue global latency gone.
__global__ __launch_bounds__(768) void k_gru(
    const _Float16* __restrict__ ah, const _Float16* __restrict__ hh,
    const _Float16* __restrict__ Bc, const float* __restrict__ b_ih,
    const float* __restrict__ b_hh, _Float16* __restrict__ hh_next,
    float* __restrict__ out_f32) {
    __shared__ float X[2][4 * 16 * LSTRIDE];         // double-buffered gate exchange
    __shared__ __align__(16) char Ast[4][8192];      // A-tile ring: [slot][ah 4KB | hh 4KB]
    const int wave = threadIdx.x >> 6, lane = threadIdx.x & 63;
    const int col16 = lane & 15, quad = lane >> 4;
    const int g = wave >> 2;                         // gate 0..2
    const int s = wave & 3;                          // col-slice of 32

    // persistent B fragments: rows (g*128 + s*32 + ct*16 + col16), k = kt*32+quad*8
    f16x8 b[2][8];
#pragma unroll
    for (int ct = 0; ct < 2; ct++) {
        const _Float16* bp = Bc + (((size_t)(g * 128 + s * 32 + ct * 16 + col16)) << 8) + quad * 8;
#pragma unroll
        for (int kt = 0; kt < 8; kt++) b[ct][kt] = *(const f16x8*)(bp + kt * 32);
    }

    // staging invariants: wave w<8 stages 1KB chunk w of the 8KB tile.
    // LDS dest is linear (base + lane*16); source is pre-swizzled so that
    // LDS[o] = tile[o ^ ((row(o)&7)<<4)], row(o)=o>>8 (256B rows).
    const int olocal = (wave & 3) * 1024 + lane * 16;   // within-part byte offset
    const int oswl = olocal ^ (((olocal >> 8) & 7) << 4);
    const char* sbase = (wave < 4) ? (const char*)ah : (const char*)hh;

    // A-frag read invariants: frag linear byte = part*4096 + col16*256 + quad*16 + (kt&3)*64
    const int abase = col16 * 256 + quad * 16;
    const int axor = (col16 & 7) << 4;

    auto STAGE = [&](int iter) {
        if (wave < 8) {
            int tt = blockIdx.x + iter * GRU_BLOCKS;
            if (tt >= GRU_TILES) tt = GRU_TILES - 1;  // clamp keeps vmcnt accounting uniform
            const char* gp = sbase + (size_t)tt * 4096 + oswl;
            char* lp = &Ast[iter & 3][wave * 1024];   // wave-uniform base; HW adds lane*16
            __builtin_amdgcn_global_load_lds(
                (const __attribute__((address_space(1))) void*)gp,
                (__attribute__((address_space(3))) void*)lp, 16, 0, 0);
        }
    };

    // prologue: prefetch iters 0 and 1; ensure iter-0 tile landed for everyone
    STAGE(0);
    STAGE(1);
    asm volatile("s_waitcnt vmcnt(1)" ::: "memory");
    __builtin_amdgcn_s_barrier();
    __builtin_amdgcn_sched_barrier(0);

    int it = 0;
    for (int tile = blockIdx.x; tile < GRU_TILES; tile += GRU_BLOCKS, ++it) {
        const int r0 = tile * 16;
        STAGE(it + 2);                               // 2-deep prefetch into ring slot

        const char* As = (const char*)Ast[it & 3];
        float* Xb = X[it & 1];

        f16x8 A[8];                                  // kt<4 = ah part, kt>=4 = hh part
#pragma unroll
        for (int kt = 0; kt < 8; kt++) {
            int off = ((kt & 4) << 10) + abase + (kt & 3) * 64;
            off ^= axor;                             // undo staging swizzle
            A[kt] = *(const f16x8*)(As + off);
        }

        f32x4 acc[2][2];                             // [khalf-set][ct]; g<2 uses set 0 only
#pragma unroll
        for (int u = 0; u < 2; u++)
#pragma unroll
            for (int ct = 0; ct < 2; ct++) acc[u][ct] = (f32x4){0.f, 0.f, 0.f, 0.f};
#pragma unroll
        for (int kt = 0; kt < 8; kt++) {
            const int set = (g == 2 && kt >= 4) ? 1 : 0;
#pragma unroll
            for (int ct = 0; ct < 2; ct++)
                acc[set][ct] = __builtin_amdgcn_mfma_f32_16x16x32_f16(
                    A[kt], b[ct][kt], acc[set][ct], 0, 0, 0);
        }

        // acc -> LDS exchange (double-buffered)
#pragma unroll
        for (int ct = 0; ct < 2; ct++) {
            const int cbase = s * 32 + ct * 16 + col16;
            if (g < 2) {
#pragma unroll
                for (int i = 0; i < 4; i++)
                    Xb[g * (16 * LSTRIDE) + (quad * 4 + i) * LSTRIDE + cbase] = acc[0][ct][i];
            } else {
#pragma unroll
                for (int i = 0; i < 4; i++) {
                    Xb[2 * (16 * LSTRIDE) + (quad * 4 + i) * LSTRIDE + cbase] = acc[0][ct][i];
                    Xb[3 * (16 * LSTRIDE) + (quad * 4 + i) * LSTRIDE + cbase] = acc[1][ct][i];
                }
            }
        }

        // ONE barrier per tile. vmcnt(1): iter+1's staging load has landed
        // (only the just-issued iter+2 load may remain in flight); lgkmcnt(0):
        // X writes visible. Prefetch is NOT drained (never vmcnt(0) in loop).
        asm volatile("s_waitcnt vmcnt(1) lgkmcnt(0)" ::: "memory");
        __builtin_amdgcn_s_barrier();
        __builtin_amdgcn_sched_barrier(0);

        // epilogue: 2048 elems over 768 threads; hprev from staged hh in LDS
#pragma unroll
        for (int pazz = 0; pazz < 3; pazz++) {
            int e = threadIdx.x + pazz * 768;
            if (e < 2048) {
                int row = e >> 7, col = e & 127;
                float vr = Xb[0 * (16 * LSTRIDE) + row * LSTRIDE + col];
                float vz = Xb[1 * (16 * LSTRIDE) + row * LSTRIDE + col];
                float vin = Xb[2 * (16 * LSTRIDE) + row * LSTRIDE + col];
                float vhn = Xb[3 * (16 * LSTRIDE) + row * LSTRIDE + col];
                float r = sigmoid_fast(vr + b_ih[col] + b_hh[col]);
                float z = sigmoid_fast(vz + b_ih[128 + col] + b_hh[128 + col]);
                float nn = tanh_fast(vin + b_ih[256 + col] + r * (vhn + b_hh[256 + col]));
                int hoff = (4096 + row * 256 + col * 2) ^ ((row & 7) << 4);
                float hprev = (float)*(const _Float16*)(As + hoff);
                float hv = (1.f - z) * nn + z * hprev;
                size_t idx = ((size_t)(r0 + row) << 7) + col;
                hh_next[idx] = (_Float16)hv;
                if (out_f32) out_f32[idx] = hv;
            }
        }
        // no second barrier: next tile writes X[it^1] and stages slot (it+3)&3,
        // both disjoint from anything a straggler still reads.
    }
    asm volatile("s_waitcnt vmcnt(0)" ::: "memory"); // drain ring prefetch before endpgm
}

// ---------------- launch ----------------

extern "C" void kernel_launch(void* const* d_in, const int* in_sizes, int n_in,
                              void* d_out, int out_size, void* d_ws, size_t ws_size,
                              hipStream_t stream) {
    const float* h0    = (const float*)d_in[0];
    const int*   src   = (const int*)d_in[1];
    const int*   dst   = (const int*)d_in[2];
    const int*   ety   = (const int*)d_in[3];
    const float* W_lin = (const float*)d_in[4];
    const float* b_lin = (const float*)d_in[5];
    const float* w_ih  = (const float*)d_in[6];
    const float* w_hh  = (const float*)d_in[7];
    const float* b_ih  = (const float*)d_in[8];
    const float* b_hh  = (const float*)d_in[9];
    float* hout = (float*)d_out;

    char* p = (char*)d_ws;
    auto alloc = [&](size_t bytes) -> char* {
        char* r = p;
        p += (bytes + 255) & ~(size_t)255;
        return r;
    };
    _Float16* h_a    = (_Float16*)alloc((size_t)N_NODES * DF * 2);
    _Float16* h_b    = (_Float16*)alloc((size_t)N_NODES * DF * 2);
    _Float16* a_half = (_Float16*)alloc((size_t)N_NODES * DF * 2);
    _Float16* t_half = (_Float16*)alloc((size_t)N_ETYPES * N_NODES * DF * 2);
    _Float16* Wl_h   = (_Float16*)alloc((size_t)N_ETYPES * DF * DF * 2);
    _Float16* Bc     = (_Float16*)alloc((size_t)3 * DF * 2 * DF * 2);   // [384][256] f16
    int* deg       = (int*)alloc((size_t)N_NODES * 4);
    int* row_start = (int*)alloc((size_t)(N_NODES + 1) * 4);
    int* cursor    = (int*)alloc((size_t)N_NODES * 4);
    int* csr       = (int*)alloc((size_t)N_EDGES * 4);
    int* part      = (int*)alloc((size_t)SCAN_NB * 4);

    hipMemsetAsync(deg, 0, (size_t)N_NODES * 4, stream);
    k_cvt_w<<<384, 256, 0, stream>>>(W_lin, w_ih, w_hh, Wl_h, Bc);
    k_cvt_h<<<(N_NODES * DF / 4 + 255) / 256, 256, 0, stream>>>(h0, h_a, N_NODES * DF / 4);
    k_hist<<<(N_EDGES + 255) / 256, 256, 0, stream>>>(dst, deg, N_EDGES);
    k_part<<<SCAN_NB, 256, 0, stream>>>(deg, part, N_NODES);
    k_scan1<<<1, 256, 0, stream>>>(part, SCAN_NB);
    k_row<<<SCAN_NB, 256, 0, stream>>>(deg, part, row_start, cursor, N_NODES);
    k_fill<<<(N_EDGES + 255) / 256, 256, 0, stream>>>(src, dst, ety, cursor, csr, N_EDGES);

    _Float16* hc = h_a;
    _Float16* hn = h_b;
    const int nb = (N_NODES + 63) / 64;              // 782
    for (int s = 0; s < N_STEPS; s++) {
        k_lin<<<dim3(nb, N_ETYPES), 256, 0, stream>>>(hc, Wl_h, b_lin, t_half, N_NODES);
        k_agg<<<N_NODES / 4, 256, 0, stream>>>(t_half, row_start, csr, a_half, N_NODES);
        float* of = (s == N_STEPS - 1) ? hout : nullptr;
        k_gru<<<GRU_BLOCKS, 768, 0, stream>>>(a_half, hc, Bc, b_ih, b_hh, hn, of);
        _Float16* tmp = hc; hc = hn; hn = tmp;
    }
}

// Round 4
// 542.209 us; speedup vs baseline: 2.3475x; 1.3365x over previous
//
#include <hip/hip_runtime.h>
#include <hip/hip_bf16.h>
#include <cstdint>
#include <cstddef>

#define N_NODES 50000
#define N_EDGES 600000
#define DF 128
#define N_ETYPES 4
#define N_STEPS 5
#define SCAN_NB 196        // ceil(50000/256)
#define GRU_TILES 3125     // 50000/16 exact
#define GRU_BLOCKS 256     // 1 block/CU (2-block residency impossible: ~140 regs/wave incl AGPR)
#define LIN_BLOCKS 256     // k_lin: 1024-thread persistent-weight blocks, grid-stride 3125 tiles
#define LSTRIDE 130        // k_gru LDS row stride (floats): 2-way bank alias only (free)
#define TSTRIDE 136        // k_lin LDS out-tile row stride (f16)

typedef _Float16 f16x8 __attribute__((ext_vector_type(8)));
typedef _Float16 f16x4 __attribute__((ext_vector_type(4)));
typedef _Float16 f16x2 __attribute__((ext_vector_type(2)));
typedef float f32x4 __attribute__((ext_vector_type(4)));

__device__ __forceinline__ float sigmoid_fast(float x) {
    return 1.0f / (1.0f + __expf(-x));
}
__device__ __forceinline__ float tanh_fast(float x) {
    return 1.0f - 2.0f / (__expf(2.0f * x) + 1.0f);
}

// ---------------- setup kernels (once per launch) ----------------

// Wl -> f16; build concatenated GRU B matrix Bc[g*128+c][k]: k<128 -> wih, else whh
__global__ __launch_bounds__(256) void k_cvt_w(
    const float* __restrict__ Wl, const float* __restrict__ wih,
    const float* __restrict__ whh, _Float16* __restrict__ Wl_h,
    _Float16* __restrict__ Bc) {
    int i = blockIdx.x * 256 + threadIdx.x;          // grid covers 98304
    if (i < N_ETYPES * DF * DF) Wl_h[i] = (_Float16)Wl[i];
    int row = i >> 8;                                // 0..383 = g*128 + c
    int k = i & 255;
    float v = (k < 128) ? wih[row * 128 + k] : whh[row * 128 + (k - 128)];
    Bc[i] = (_Float16)v;
}

__global__ __launch_bounds__(256) void k_cvt_h(
    const float* __restrict__ h, _Float16* __restrict__ hh, int n4) {
    int i = blockIdx.x * 256 + threadIdx.x;
    if (i < n4) {
        float4 v = ((const float4*)h)[i];
        f16x4 o;
        o.x = (_Float16)v.x; o.y = (_Float16)v.y;
        o.z = (_Float16)v.z; o.w = (_Float16)v.w;
        ((f16x4*)hh)[i] = o;
    }
}

__global__ __launch_bounds__(256) void k_hist(
    const int* __restrict__ dst, int* __restrict__ deg, int E) {
    int i = blockIdx.x * 256 + threadIdx.x;
    if (i < E) atomicAdd(&deg[dst[i]], 1);
}

// hierarchical exclusive scan over deg[0..N)
__global__ __launch_bounds__(256) void k_part(
    const int* __restrict__ deg, int* __restrict__ part, int N) {
    __shared__ int s[256];
    int t = threadIdx.x, i = blockIdx.x * 256 + t;
    s[t] = (i < N) ? deg[i] : 0;
    __syncthreads();
    for (int off = 128; off > 0; off >>= 1) {
        if (t < off) s[t] += s[t + off];
        __syncthreads();
    }
    if (t == 0) part[blockIdx.x] = s[0];
}

__global__ __launch_bounds__(256) void k_scan1(int* __restrict__ part, int nb) {
    __shared__ int s[256];
    int t = threadIdx.x;
    int v = (t < nb) ? part[t] : 0;
    s[t] = v;
    __syncthreads();
    for (int off = 1; off < 256; off <<= 1) {
        int u = (t >= off) ? s[t - off] : 0;
        __syncthreads();
        s[t] += u;
        __syncthreads();
    }
    if (t < nb) part[t] = s[t] - v;
}

__global__ __launch_bounds__(256) void k_row(
    const int* __restrict__ deg, const int* __restrict__ part,
    int* __restrict__ row_start, int* __restrict__ cursor, int N) {
    __shared__ int s[256];
    int t = threadIdx.x, i = blockIdx.x * 256 + t;
    int d = (i < N) ? deg[i] : 0;
    s[t] = d;
    __syncthreads();
    for (int off = 1; off < 256; off <<= 1) {
        int u = (t >= off) ? s[t - off] : 0;
        __syncthreads();
        s[t] += u;
        __syncthreads();
    }
    int rs = part[blockIdx.x] + s[t] - d;
    if (i < N) {
        row_start[i] = rs;
        cursor[i] = rs;
        if (i == N - 1) row_start[N] = rs + d;
    }
}

__global__ __launch_bounds__(256) void k_fill(
    const int* __restrict__ src, const int* __restrict__ dst,
    const int* __restrict__ ety, int* __restrict__ cursor,
    int* __restrict__ csr, int E) {
    int i = blockIdx.x * 256 + threadIdx.x;
    if (i < E) {
        int slot = atomicAdd(&cursor[dst[i]], 1);
        csr[slot] = src[i] | ((ety[i] - 1) << 16);   // src < 65536, et in 0..3
    }
}

// ---------------- per-step kernels ----------------

// t[k][n][f] = sum_d h[n,d] * W[k][f,d] + b_lin[k][f]   (f16 h in, f16 out)
// REWRITTEN (k_gru architecture): 16 waves = 4 etypes x 4 col-slices; each
// wave's 32-col W-slice (8 f16x8 = 32 VGPRs) persistent in registers across a
// grid-stride tile loop -> W read ONCE per block, not 32 global loads per wave
// on the MFMA critical path. h-tile (4KB) staged via global_load_lds into a
// 4-slot XOR-swizzled ring 2 tiles ahead; one counted-vmcnt barrier per tile;
// double-buffered LDS out-tile -> contiguous f16x8 stores (one per thread).
__global__ __launch_bounds__(1024) void k_lin(
    const _Float16* __restrict__ hh, const _Float16* __restrict__ Wl,
    const float* __restrict__ b_lin, _Float16* __restrict__ t_out, int N) {
    __shared__ _Float16 O[2][N_ETYPES * 16 * TSTRIDE];   // double-buffered out-tile
    __shared__ __align__(16) char Ast[4][4096];          // h-tile ring (16 rows x 256B)
    const int wave = threadIdx.x >> 6, lane = threadIdx.x & 63;
    const int col16 = lane & 15, quad = lane >> 4;
    const int g = wave >> 2;                         // etype 0..3
    const int s = wave & 3;                          // col-slice of 32

    // persistent W fragments: rows (s*32 + ct*16 + col16) of W[g], k = kt*32+quad*8
    f16x8 b[2][4];
#pragma unroll
    for (int ct = 0; ct < 2; ct++) {
        const _Float16* bp = Wl + (size_t)g * DF * DF
                           + (size_t)(s * 32 + ct * 16 + col16) * DF + quad * 8;
#pragma unroll
        for (int kt = 0; kt < 4; kt++) b[ct][kt] = *(const f16x8*)(bp + kt * 32);
    }
    const float bias0 = b_lin[g * DF + s * 32 + col16];
    const float bias1 = b_lin[g * DF + s * 32 + 16 + col16];

    // staging: waves 0-3 stage 1KB each; LDS dest linear, SOURCE pre-swizzled so
    // LDS[o] = tile[o ^ ((row(o)&7)<<4)], row(o)=o>>8 (256B rows).
    const int olocal = (wave & 3) * 1024 + lane * 16;
    const int oswl = olocal ^ (((olocal >> 8) & 7) << 4);

    // A-frag read: linear byte = col16*256 + quad*16 + kt*64, XOR undoes swizzle
    const int abase = col16 * 256 + quad * 16;
    const int axor = (col16 & 7) << 4;

    auto STAGE = [&](int iter) {
        if (wave < 4) {
            int tt = blockIdx.x + iter * LIN_BLOCKS;
            if (tt >= GRU_TILES) tt = GRU_TILES - 1; // clamp keeps vmcnt accounting uniform
            const char* gp = (const char*)hh + (size_t)tt * 4096 + oswl;
            char* lp = &Ast[iter & 3][(wave & 3) * 1024];
            __builtin_amdgcn_global_load_lds(
                (const __attribute__((address_space(1))) void*)gp,
                (__attribute__((address_space(3))) void*)lp, 16, 0, 0);
        }
    };

    // epilogue store mapping: one f16x8 chunk per thread (4*16*16 = 1024 chunks)
    const int ek = threadIdx.x >> 8;                 // etype
    const int erow = (threadIdx.x & 255) >> 4;       // row 0..15
    const int ec8 = threadIdx.x & 15;                // col chunk

    STAGE(0);
    STAGE(1);
    asm volatile("s_waitcnt vmcnt(1)" ::: "memory");
    __builtin_amdgcn_s_barrier();
    __builtin_amdgcn_sched_barrier(0);

    int it = 0;
    for (int tile = blockIdx.x; tile < GRU_TILES; tile += LIN_BLOCKS, ++it) {
        const int r0 = tile * 16;
        STAGE(it + 2);                               // 2-deep prefetch

        const char* As = (const char*)Ast[it & 3];
        _Float16* Ob = O[it & 1];

        f16x8 A[4];
#pragma unroll
        for (int kt = 0; kt < 4; kt++) {
            int off = (abase + kt * 64) ^ axor;
            A[kt] = *(const f16x8*)(As + off);
        }

        f32x4 acc0 = {0.f, 0.f, 0.f, 0.f}, acc1 = {0.f, 0.f, 0.f, 0.f};
#pragma unroll
        for (int kt = 0; kt < 4; kt++) {
            acc0 = __builtin_amdgcn_mfma_f32_16x16x32_f16(A[kt], b[0][kt], acc0, 0, 0, 0);
            acc1 = __builtin_amdgcn_mfma_f32_16x16x32_f16(A[kt], b[1][kt], acc1, 0, 0, 0);
        }

        // bias + f16 -> LDS out-tile (C layout: row=quad*4+i, col=s*32+ct*16+col16)
        _Float16* Og = Ob + g * (16 * TSTRIDE);
#pragma unroll
        for (int i = 0; i < 4; i++) {
            Og[(quad * 4 + i) * TSTRIDE + s * 32 + col16] = (_Float16)(acc0[i] + bias0);
            Og[(quad * 4 + i) * TSTRIDE + s * 32 + 16 + col16] = (_Float16)(acc1[i] + bias1);
        }

        // ONE barrier per tile; vmcnt(1) keeps the newest prefetch in flight.
        asm volatile("s_waitcnt vmcnt(1) lgkmcnt(0)" ::: "memory");
        __builtin_amdgcn_s_barrier();
        __builtin_amdgcn_sched_barrier(0);

        // store: per wave = 4 rows x 256B contiguous
        f16x8 v = *(const f16x8*)&Ob[ek * (16 * TSTRIDE) + erow * TSTRIDE + ec8 * 8];
        *(f16x8*)(t_out + ((size_t)ek * N + (r0 + erow)) * DF + ec8 * 8) = v;
        // no second barrier: next tile writes O[it^1] / stages slot (it+3)&3,
        // both disjoint; O[it&1] rewritten only at it+2, after the it+1 barrier.
    }
    asm volatile("s_waitcnt vmcnt(0)" ::: "memory"); // drain ring prefetch before endpgm
}

// a[n][:] = sum over incoming edges of t[et][src][:]  -> f16
__global__ __launch_bounds__(256) void k_agg(
    const _Float16* __restrict__ t, const int* __restrict__ row_start,
    const int* __restrict__ csr, _Float16* __restrict__ ah, int N) {
    const int wave = threadIdx.x >> 6, lane = threadIdx.x & 63;
    const int g4 = lane >> 4;                        // edge slot 0..3
    const int c8 = lane & 15;                        // col chunk: cols c8*8..+7
    const int n = blockIdx.x * 4 + wave;             // grid = N/4 exactly
    const int beg = row_start[n], end = row_start[n + 1];
    float acc[8] = {0.f, 0.f, 0.f, 0.f, 0.f, 0.f, 0.f, 0.f};
    for (int e = beg; e < end; e += 16) {
        int i0 = e + g4, i1 = e + 4 + g4, i2 = e + 8 + g4, i3 = e + 12 + g4;
        float m0 = (i0 < end) ? 1.0f : 0.0f;
        float m1 = (i1 < end) ? 1.0f : 0.0f;
        float m2 = (i2 < end) ? 1.0f : 0.0f;
        float m3 = (i3 < end) ? 1.0f : 0.0f;
        int j0 = (i0 < end) ? i0 : end - 1;
        int j1 = (i1 < end) ? i1 : end - 1;
        int j2 = (i2 < end) ? i2 : end - 1;
        int j3 = (i3 < end) ? i3 : end - 1;
        int p0 = csr[j0], p1 = csr[j1], p2 = csr[j2], p3 = csr[j3];
        f16x8 x0 = *(const f16x8*)(t + ((((size_t)(p0 >> 16)) * N + (p0 & 0xFFFF)) << 7) + c8 * 8);
        f16x8 x1 = *(const f16x8*)(t + ((((size_t)(p1 >> 16)) * N + (p1 & 0xFFFF)) << 7) + c8 * 8);
        f16x8 x2 = *(const f16x8*)(t + ((((size_t)(p2 >> 16)) * N + (p2 & 0xFFFF)) << 7) + c8 * 8);
        f16x8 x3 = *(const f16x8*)(t + ((((size_t)(p3 >> 16)) * N + (p3 & 0xFFFF)) << 7) + c8 * 8);
#pragma unroll
        for (int j = 0; j < 8; j++) acc[j] += m0 * (float)x0[j];
#pragma unroll
        for (int j = 0; j < 8; j++) acc[j] += m1 * (float)x1[j];
#pragma unroll
        for (int j = 0; j < 8; j++) acc[j] += m2 * (float)x2[j];
#pragma unroll
        for (int j = 0; j < 8; j++) acc[j] += m3 * (float)x3[j];
    }
#pragma unroll
    for (int j = 0; j < 8; j++) {
        acc[j] += __shfl_xor(acc[j], 32, 64);
        acc[j] += __shfl_xor(acc[j], 16, 64);
    }
    if (lane < 16) {
        f16x8 o;
#pragma unroll
        for (int j = 0; j < 8; j++) o[j] = (_Float16)acc[j];
        *(f16x8*)(ah + ((size_t)n << 7) + c8 * 8) = o;
    }
}

// GRU, gate-parallel, software-pipelined (unchanged from R3 — verified win).
__global__ __launch_bounds__(768) void k_gru(
    const _Float16* __restrict__ ah, const _Float16* __restrict__ hh,
    const _Float16* __restrict__ Bc, const float* __restrict__ b_ih,
    const float* __restrict__ b_hh, _Float16* __restrict__ hh_next,
    float* __restrict__ out_f32) {
    __shared__ float X[2][4 * 16 * LSTRIDE];         // double-buffered gate exchange
    __shared__ __align__(16) char Ast[4][8192];      // A-tile ring: [slot][ah 4KB | hh 4KB]
    const int wave = threadIdx.x >> 6, lane = threadIdx.x & 63;
    const int col16 = lane & 15, quad = lane >> 4;
    const int g = wave >> 2;                         // gate 0..2
    const int s = wave & 3;                          // col-slice of 32

    // persistent B fragments: rows (g*128 + s*32 + ct*16 + col16), k = kt*32+quad*8
    f16x8 b[2][8];
#pragma unroll
    for (int ct = 0; ct < 2; ct++) {
        const _Float16* bp = Bc + (((size_t)(g * 128 + s * 32 + ct * 16 + col16)) << 8) + quad * 8;
#pragma unroll
        for (int kt = 0; kt < 8; kt++) b[ct][kt] = *(const f16x8*)(bp + kt * 32);
    }

    const int olocal = (wave & 3) * 1024 + lane * 16;   // within-part byte offset
    const int oswl = olocal ^ (((olocal >> 8) & 7) << 4);
    const char* sbase = (wave < 4) ? (const char*)ah : (const char*)hh;

    const int abase = col16 * 256 + quad * 16;
    const int axor = (col16 & 7) << 4;

    auto STAGE = [&](int iter) {
        if (wave < 8) {
            int tt = blockIdx.x + iter * GRU_BLOCKS;
            if (tt >= GRU_TILES) tt = GRU_TILES - 1;  // clamp keeps vmcnt accounting uniform
            const char* gp = sbase + (size_t)tt * 4096 + oswl;
            char* lp = &Ast[iter & 3][wave * 1024];   // wave-uniform base; HW adds lane*16
            __builtin_amdgcn_global_load_lds(
                (const __attribute__((address_space(1))) void*)gp,
                (__attribute__((address_space(3))) void*)lp, 16, 0, 0);
        }
    };

    STAGE(0);
    STAGE(1);
    asm volatile("s_waitcnt vmcnt(1)" ::: "memory");
    __builtin_amdgcn_s_barrier();
    __builtin_amdgcn_sched_barrier(0);

    int it = 0;
    for (int tile = blockIdx.x; tile < GRU_TILES; tile += GRU_BLOCKS, ++it) {
        const int r0 = tile * 16;
        STAGE(it + 2);                               // 2-deep prefetch into ring slot

        const char* As = (const char*)Ast[it & 3];
        float* Xb = X[it & 1];

        f16x8 A[8];                                  // kt<4 = ah part, kt>=4 = hh part
#pragma unroll
        for (int kt = 0; kt < 8; kt++) {
            int off = ((kt & 4) << 10) + abase + (kt & 3) * 64;
            off ^= axor;                             // undo staging swizzle
            A[kt] = *(const f16x8*)(As + off);
        }

        f32x4 acc[2][2];                             // [khalf-set][ct]; g<2 uses set 0 only
#pragma unroll
        for (int u = 0; u < 2; u++)
#pragma unroll
            for (int ct = 0; ct < 2; ct++) acc[u][ct] = (f32x4){0.f, 0.f, 0.f, 0.f};
#pragma unroll
        for (int kt = 0; kt < 8; kt++) {
            const int set = (g == 2 && kt >= 4) ? 1 : 0;
#pragma unroll
            for (int ct = 0; ct < 2; ct++)
                acc[set][ct] = __builtin_amdgcn_mfma_f32_16x16x32_f16(
                    A[kt], b[ct][kt], acc[set][ct], 0, 0, 0);
        }

        // acc -> LDS exchange (double-buffered)
#pragma unroll
        for (int ct = 0; ct < 2; ct++) {
            const int cbase = s * 32 + ct * 16 + col16;
            if (g < 2) {
#pragma unroll
                for (int i = 0; i < 4; i++)
                    Xb[g * (16 * LSTRIDE) + (quad * 4 + i) * LSTRIDE + cbase] = acc[0][ct][i];
            } else {
#pragma unroll
                for (int i = 0; i < 4; i++) {
                    Xb[2 * (16 * LSTRIDE) + (quad * 4 + i) * LSTRIDE + cbase] = acc[0][ct][i];
                    Xb[3 * (16 * LSTRIDE) + (quad * 4 + i) * LSTRIDE + cbase] = acc[1][ct][i];
                }
            }
        }

        asm volatile("s_waitcnt vmcnt(1) lgkmcnt(0)" ::: "memory");
        __builtin_amdgcn_s_barrier();
        __builtin_amdgcn_sched_barrier(0);

        // epilogue: 2048 elems over 768 threads; hprev from staged hh in LDS
#pragma unroll
        for (int pazz = 0; pazz < 3; pazz++) {
            int e = threadIdx.x + pazz * 768;
            if (e < 2048) {
                int row = e >> 7, col = e & 127;
                float vr = Xb[0 * (16 * LSTRIDE) + row * LSTRIDE + col];
                float vz = Xb[1 * (16 * LSTRIDE) + row * LSTRIDE + col];
                float vin = Xb[2 * (16 * LSTRIDE) + row * LSTRIDE + col];
                float vhn = Xb[3 * (16 * LSTRIDE) + row * LSTRIDE + col];
                float r = sigmoid_fast(vr + b_ih[col] + b_hh[col]);
                float z = sigmoid_fast(vz + b_ih[128 + col] + b_hh[128 + col]);
                float nn = tanh_fast(vin + b_ih[256 + col] + r * (vhn + b_hh[256 + col]));
                int hoff = (4096 + row * 256 + col * 2) ^ ((row & 7) << 4);
                float hprev = (float)*(const _Float16*)(As + hoff);
                float hv = (1.f - z) * nn + z * hprev;
                size_t idx = ((size_t)(r0 + row) << 7) + col;
                hh_next[idx] = (_Float16)hv;
                if (out_f32) out_f32[idx] = hv;
            }
        }
    }
    asm volatile("s_waitcnt vmcnt(0)" ::: "memory"); // drain ring prefetch before endpgm
}

// ---------------- launch ----------------

extern "C" void kernel_launch(void* const* d_in, const int* in_sizes, int n_in,
                              void* d_out, int out_size, void* d_ws, size_t ws_size,
                              hipStream_t stream) {
    const float* h0    = (const float*)d_in[0];
    const int*   src   = (const int*)d_in[1];
    const int*   dst   = (const int*)d_in[2];
    const int*   ety   = (const int*)d_in[3];
    const float* W_lin = (const float*)d_in[4];
    const float* b_lin = (const float*)d_in[5];
    const float* w_ih  = (const float*)d_in[6];
    const float* w_hh  = (const float*)d_in[7];
    const float* b_ih  = (const float*)d_in[8];
    const float* b_hh  = (const float*)d_in[9];
    float* hout = (float*)d_out;

    char* p = (char*)d_ws;
    auto alloc = [&](size_t bytes) -> char* {
        char* r = p;
        p += (bytes + 255) & ~(size_t)255;
        return r;
    };
    _Float16* h_a    = (_Float16*)alloc((size_t)N_NODES * DF * 2);
    _Float16* h_b    = (_Float16*)alloc((size_t)N_NODES * DF * 2);
    _Float16* a_half = (_Float16*)alloc((size_t)N_NODES * DF * 2);
    _Float16* t_half = (_Float16*)alloc((size_t)N_ETYPES * N_NODES * DF * 2);
    _Float16* Wl_h   = (_Float16*)alloc((size_t)N_ETYPES * DF * DF * 2);
    _Float16* Bc     = (_Float16*)alloc((size_t)3 * DF * 2 * DF * 2);   // [384][256] f16
    int* deg       = (int*)alloc((size_t)N_NODES * 4);
    int* row_start = (int*)alloc((size_t)(N_NODES + 1) * 4);
    int* cursor    = (int*)alloc((size_t)N_NODES * 4);
    int* csr       = (int*)alloc((size_t)N_EDGES * 4);
    int* part      = (int*)alloc((size_t)SCAN_NB * 4);

    hipMemsetAsync(deg, 0, (size_t)N_NODES * 4, stream);
    k_cvt_w<<<384, 256, 0, stream>>>(W_lin, w_ih, w_hh, Wl_h, Bc);
    k_cvt_h<<<(N_NODES * DF / 4 + 255) / 256, 256, 0, stream>>>(h0, h_a, N_NODES * DF / 4);
    k_hist<<<(N_EDGES + 255) / 256, 256, 0, stream>>>(dst, deg, N_EDGES);
    k_part<<<SCAN_NB, 256, 0, stream>>>(deg, part, N_NODES);
    k_scan1<<<1, 256, 0, stream>>>(part, SCAN_NB);
    k_row<<<SCAN_NB, 256, 0, stream>>>(deg, part, row_start, cursor, N_NODES);
    k_fill<<<(N_EDGES + 255) / 256, 256, 0, stream>>>(src, dst, ety, cursor, csr, N_EDGES);

    _Float16* hc = h_a;
    _Float16* hn = h_b;
    for (int s = 0; s < N_STEPS; s++) {
        k_lin<<<LIN_BLOCKS, 1024, 0, stream>>>(hc, Wl_h, b_lin, t_half, N_NODES);
        k_agg<<<N_NODES / 4, 256, 0, stream>>>(t_half, row_start, csr, a_half, N_NODES);
        float* of = (s == N_STEPS - 1) ? hout : nullptr;
        k_gru<<<GRU_BLOCKS, 768, 0, stream>>>(a_half, hc, Bc, b_ih, b_hh, hn, of);
        _Float16* tmp = hc; hc = hn; hn = tmp;
    }
}

// Round 5
// 534.017 us; speedup vs baseline: 2.3835x; 1.0153x over previous
//
#include <hip/hip_runtime.h>
#include <hip/hip_bf16.h>
#include <cstdint>
#include <cstddef>

#define N_NODES 50000
#define N_EDGES 600000
#define DF 128
#define N_ETYPES 4
#define N_STEPS 5
#define SCAN_NB 196        // ceil(50000/256)
#define GRU_TILES 3125     // 50000/16 exact
#define GRU_BLOCKS 256     // 1 block/CU (2-block residency impossible: ~140 regs/wave incl AGPR)
#define LIN_BLOCKS 256     // k_lin: 1024-thread persistent-weight blocks, grid-stride 3125 tiles
#define LSTRIDE 130        // k_gru LDS row stride (floats): 2-way bank alias only (free)
#define TSTRIDE 136        // k_lin LDS out-tile row stride (f16)
#define FILL_CHUNKS 2344   // ceil(600000/256)
#define FILL_RANGE (N_NODES / 8)   // 6250 nodes per XCD range

typedef _Float16 f16x8 __attribute__((ext_vector_type(8)));
typedef _Float16 f16x4 __attribute__((ext_vector_type(4)));
typedef _Float16 f16x2 __attribute__((ext_vector_type(2)));
typedef float f32x4 __attribute__((ext_vector_type(4)));

__device__ __forceinline__ float sigmoid_fast(float x) {
    return 1.0f / (1.0f + __expf(-x));
}
__device__ __forceinline__ float tanh_fast(float x) {
    return 1.0f - 2.0f / (__expf(2.0f * x) + 1.0f);
}

// ---------------- setup kernels (once per launch) ----------------

// Wl -> f16; build concatenated GRU B matrix Bc[g*128+c][k]: k<128 -> wih, else whh
__global__ __launch_bounds__(256) void k_cvt_w(
    const float* __restrict__ Wl, const float* __restrict__ wih,
    const float* __restrict__ whh, _Float16* __restrict__ Wl_h,
    _Float16* __restrict__ Bc) {
    int i = blockIdx.x * 256 + threadIdx.x;          // grid covers 98304
    if (i < N_ETYPES * DF * DF) Wl_h[i] = (_Float16)Wl[i];
    int row = i >> 8;                                // 0..383 = g*128 + c
    int k = i & 255;
    float v = (k < 128) ? wih[row * 128 + k] : whh[row * 128 + (k - 128)];
    Bc[i] = (_Float16)v;
}

__global__ __launch_bounds__(256) void k_cvt_h(
    const float* __restrict__ h, _Float16* __restrict__ hh, int n4) {
    int i = blockIdx.x * 256 + threadIdx.x;
    if (i < n4) {
        float4 v = ((const float4*)h)[i];
        f16x4 o;
        o.x = (_Float16)v.x; o.y = (_Float16)v.y;
        o.z = (_Float16)v.z; o.w = (_Float16)v.w;
        ((f16x4*)hh)[i] = o;
    }
}

__global__ __launch_bounds__(256) void k_hist(
    const int* __restrict__ dst, int* __restrict__ deg, int E) {
    int i = blockIdx.x * 256 + threadIdx.x;
    if (i < E) atomicAdd(&deg[dst[i]], 1);
}

// hierarchical exclusive scan over deg[0..N)
__global__ __launch_bounds__(256) void k_part(
    const int* __restrict__ deg, int* __restrict__ part, int N) {
    __shared__ int s[256];
    int t = threadIdx.x, i = blockIdx.x * 256 + t;
    s[t] = (i < N) ? deg[i] : 0;
    __syncthreads();
    for (int off = 128; off > 0; off >>= 1) {
        if (t < off) s[t] += s[t + off];
        __syncthreads();
    }
    if (t == 0) part[blockIdx.x] = s[0];
}

__global__ __launch_bounds__(256) void k_scan1(int* __restrict__ part, int nb) {
    __shared__ int s[256];
    int t = threadIdx.x;
    int v = (t < nb) ? part[t] : 0;
    s[t] = v;
    __syncthreads();
    for (int off = 1; off < 256; off <<= 1) {
        int u = (t >= off) ? s[t - off] : 0;
        __syncthreads();
        s[t] += u;
        __syncthreads();
    }
    if (t < nb) part[t] = s[t] - v;
}

__global__ __launch_bounds__(256) void k_row(
    const int* __restrict__ deg, const int* __restrict__ part,
    int* __restrict__ row_start, int* __restrict__ cursor, int N) {
    __shared__ int s[256];
    int t = threadIdx.x, i = blockIdx.x * 256 + t;
    int d = (i < N) ? deg[i] : 0;
    s[t] = d;
    __syncthreads();
    for (int off = 1; off < 256; off <<= 1) {
        int u = (t >= off) ? s[t - off] : 0;
        __syncthreads();
        s[t] += u;
        __syncthreads();
    }
    int rs = part[blockIdx.x] + s[t] - d;
    if (i < N) {
        row_start[i] = rs;
        cursor[i] = rs;
        if (i == N - 1) row_start[N] = rs + d;
    }
}

// XCD-partitioned CSR scatter. Old version: every 4B store scattered across all
// 8 XCDs -> per-XCD L2s can't accumulate partial lines -> 64B write-through per
// store (WRITE_SIZE 36.7MB for 2.4MB payload, 15x amplification). Now: 8 blocks
// per 256-edge chunk; block handles node range (blockIdx&7)*6250..+6250. With
// round-robin blockIdx->XCD, each contiguous csr segment (~300KB) is written by
// ONE XCD -> lines fill in that L2 -> ~1x write-back. Every (edge,range) pair
// is processed exactly once regardless of the actual XCD mapping (correctness
// does not depend on scheduler behavior; only locality does). dst re-read 8x
// (19.2MB, L2/L3-resident).
__global__ __launch_bounds__(256) void k_fill(
    const int* __restrict__ src, const int* __restrict__ dst,
    const int* __restrict__ ety, int* __restrict__ cursor,
    int* __restrict__ csr, int E) {
    const int range = blockIdx.x & 7;
    const int chunk = blockIdx.x >> 3;
    const int e = chunk * 256 + threadIdx.x;
    const int lo = range * FILL_RANGE;
    const int hi = lo + FILL_RANGE;
    if (e < E) {
        int d = dst[e];
        if (d >= lo && d < hi) {
            int slot = atomicAdd(&cursor[d], 1);
            csr[slot] = src[e] | ((ety[e] - 1) << 16);   // src < 65536, et in 0..3
        }
    }
}

// ---------------- per-step kernels ----------------

// t[k][n][f] = sum_d h[n,d] * W[k][f,d] + b_lin[k][f]   (f16 h in, f16 out)
// 16 waves = 4 etypes x 4 col-slices; W-slices persistent in VGPRs across a
// grid-stride tile loop; h-tile staged via global_load_lds ring (R4 win).
__global__ __launch_bounds__(1024) void k_lin(
    const _Float16* __restrict__ hh, const _Float16* __restrict__ Wl,
    const float* __restrict__ b_lin, _Float16* __restrict__ t_out, int N) {
    __shared__ _Float16 O[2][N_ETYPES * 16 * TSTRIDE];   // double-buffered out-tile
    __shared__ __align__(16) char Ast[4][4096];          // h-tile ring (16 rows x 256B)
    const int wave = threadIdx.x >> 6, lane = threadIdx.x & 63;
    const int col16 = lane & 15, quad = lane >> 4;
    const int g = wave >> 2;                         // etype 0..3
    const int s = wave & 3;                          // col-slice of 32

    // persistent W fragments: rows (s*32 + ct*16 + col16) of W[g], k = kt*32+quad*8
    f16x8 b[2][4];
#pragma unroll
    for (int ct = 0; ct < 2; ct++) {
        const _Float16* bp = Wl + (size_t)g * DF * DF
                           + (size_t)(s * 32 + ct * 16 + col16) * DF + quad * 8;
#pragma unroll
        for (int kt = 0; kt < 4; kt++) b[ct][kt] = *(const f16x8*)(bp + kt * 32);
    }
    const float bias0 = b_lin[g * DF + s * 32 + col16];
    const float bias1 = b_lin[g * DF + s * 32 + 16 + col16];

    // staging: waves 0-3 stage 1KB each; LDS dest linear, SOURCE pre-swizzled so
    // LDS[o] = tile[o ^ ((row(o)&7)<<4)], row(o)=o>>8 (256B rows).
    const int olocal = (wave & 3) * 1024 + lane * 16;
    const int oswl = olocal ^ (((olocal >> 8) & 7) << 4);

    // A-frag read: linear byte = col16*256 + quad*16 + kt*64, XOR undoes swizzle
    const int abase = col16 * 256 + quad * 16;
    const int axor = (col16 & 7) << 4;

    auto STAGE = [&](int iter) {
        if (wave < 4) {
            int tt = blockIdx.x + iter * LIN_BLOCKS;
            if (tt >= GRU_TILES) tt = GRU_TILES - 1; // clamp keeps vmcnt accounting uniform
            const char* gp = (const char*)hh + (size_t)tt * 4096 + oswl;
            char* lp = &Ast[iter & 3][(wave & 3) * 1024];
            __builtin_amdgcn_global_load_lds(
                (const __attribute__((address_space(1))) void*)gp,
                (__attribute__((address_space(3))) void*)lp, 16, 0, 0);
        }
    };

    // epilogue store mapping: one f16x8 chunk per thread (4*16*16 = 1024 chunks)
    const int ek = threadIdx.x >> 8;                 // etype
    const int erow = (threadIdx.x & 255) >> 4;       // row 0..15
    const int ec8 = threadIdx.x & 15;                // col chunk

    STAGE(0);
    STAGE(1);
    asm volatile("s_waitcnt vmcnt(1)" ::: "memory");
    __builtin_amdgcn_s_barrier();
    __builtin_amdgcn_sched_barrier(0);

    int it = 0;
    for (int tile = blockIdx.x; tile < GRU_TILES; tile += LIN_BLOCKS, ++it) {
        const int r0 = tile * 16;
        STAGE(it + 2);                               // 2-deep prefetch

        const char* As = (const char*)Ast[it & 3];
        _Float16* Ob = O[it & 1];

        f16x8 A[4];
#pragma unroll
        for (int kt = 0; kt < 4; kt++) {
            int off = (abase + kt * 64) ^ axor;
            A[kt] = *(const f16x8*)(As + off);
        }

        f32x4 acc0 = {0.f, 0.f, 0.f, 0.f}, acc1 = {0.f, 0.f, 0.f, 0.f};
#pragma unroll
        for (int kt = 0; kt < 4; kt++) {
            acc0 = __builtin_amdgcn_mfma_f32_16x16x32_f16(A[kt], b[0][kt], acc0, 0, 0, 0);
            acc1 = __builtin_amdgcn_mfma_f32_16x16x32_f16(A[kt], b[1][kt], acc1, 0, 0, 0);
        }

        // bias + f16 -> LDS out-tile (C layout: row=quad*4+i, col=s*32+ct*16+col16)
        _Float16* Og = Ob + g * (16 * TSTRIDE);
#pragma unroll
        for (int i = 0; i < 4; i++) {
            Og[(quad * 4 + i) * TSTRIDE + s * 32 + col16] = (_Float16)(acc0[i] + bias0);
            Og[(quad * 4 + i) * TSTRIDE + s * 32 + 16 + col16] = (_Float16)(acc1[i] + bias1);
        }

        // ONE barrier per tile; vmcnt(1) keeps the newest prefetch in flight.
        asm volatile("s_waitcnt vmcnt(1) lgkmcnt(0)" ::: "memory");
        __builtin_amdgcn_s_barrier();
        __builtin_amdgcn_sched_barrier(0);

        // store: per wave = 4 rows x 256B contiguous
        f16x8 v = *(const f16x8*)&Ob[ek * (16 * TSTRIDE) + erow * TSTRIDE + ec8 * 8];
        *(f16x8*)(t_out + ((size_t)ek * N + (r0 + erow)) * DF + ec8 * 8) = v;
        // no second barrier: next tile writes O[it^1] / stages slot (it+3)&3,
        // both disjoint; O[it&1] rewritten only at it+2, after the it+1 barrier.
    }
    asm volatile("s_waitcnt vmcnt(0)" ::: "memory"); // drain ring prefetch before endpgm
}

// a[n][:] = sum over incoming edges of t[et][src][:]  -> f16
__global__ __launch_bounds__(256) void k_agg(
    const _Float16* __restrict__ t, const int* __restrict__ row_start,
    const int* __restrict__ csr, _Float16* __restrict__ ah, int N) {
    const int wave = threadIdx.x >> 6, lane = threadIdx.x & 63;
    const int g4 = lane >> 4;                        // edge slot 0..3
    const int c8 = lane & 15;                        // col chunk: cols c8*8..+7
    const int n = blockIdx.x * 4 + wave;             // grid = N/4 exactly
    const int beg = row_start[n], end = row_start[n + 1];
    float acc[8] = {0.f, 0.f, 0.f, 0.f, 0.f, 0.f, 0.f, 0.f};
    for (int e = beg; e < end; e += 16) {
        int i0 = e + g4, i1 = e + 4 + g4, i2 = e + 8 + g4, i3 = e + 12 + g4;
        float m0 = (i0 < end) ? 1.0f : 0.0f;
        float m1 = (i1 < end) ? 1.0f : 0.0f;
        float m2 = (i2 < end) ? 1.0f : 0.0f;
        float m3 = (i3 < end) ? 1.0f : 0.0f;
        int j0 = (i0 < end) ? i0 : end - 1;
        int j1 = (i1 < end) ? i1 : end - 1;
        int j2 = (i2 < end) ? i2 : end - 1;
        int j3 = (i3 < end) ? i3 : end - 1;
        int p0 = csr[j0], p1 = csr[j1], p2 = csr[j2], p3 = csr[j3];
        f16x8 x0 = *(const f16x8*)(t + ((((size_t)(p0 >> 16)) * N + (p0 & 0xFFFF)) << 7) + c8 * 8);
        f16x8 x1 = *(const f16x8*)(t + ((((size_t)(p1 >> 16)) * N + (p1 & 0xFFFF)) << 7) + c8 * 8);
        f16x8 x2 = *(const f16x8*)(t + ((((size_t)(p2 >> 16)) * N + (p2 & 0xFFFF)) << 7) + c8 * 8);
        f16x8 x3 = *(const f16x8*)(t + ((((size_t)(p3 >> 16)) * N + (p3 & 0xFFFF)) << 7) + c8 * 8);
#pragma unroll
        for (int j = 0; j < 8; j++) acc[j] += m0 * (float)x0[j];
#pragma unroll
        for (int j = 0; j < 8; j++) acc[j] += m1 * (float)x1[j];
#pragma unroll
        for (int j = 0; j < 8; j++) acc[j] += m2 * (float)x2[j];
#pragma unroll
        for (int j = 0; j < 8; j++) acc[j] += m3 * (float)x3[j];
    }
#pragma unroll
    for (int j = 0; j < 8; j++) {
        acc[j] += __shfl_xor(acc[j], 32, 64);
        acc[j] += __shfl_xor(acc[j], 16, 64);
    }
    if (lane < 16) {
        f16x8 o;
#pragma unroll
        for (int j = 0; j < 8; j++) o[j] = (_Float16)acc[j];
        *(f16x8*)(ah + ((size_t)n << 7) + c8 * 8) = o;
    }
}

// GRU, gate-parallel, software-pipelined (unchanged from R3 — verified win).
__global__ __launch_bounds__(768) void k_gru(
    const _Float16* __restrict__ ah, const _Float16* __restrict__ hh,
    const _Float16* __restrict__ Bc, const float* __restrict__ b_ih,
    const float* __restrict__ b_hh, _Float16* __restrict__ hh_next,
    float* __restrict__ out_f32) {
    __shared__ float X[2][4 * 16 * LSTRIDE];         // double-buffered gate exchange
    __shared__ __align__(16) char Ast[4][8192];      // A-tile ring: [slot][ah 4KB | hh 4KB]
    const int wave = threadIdx.x >> 6, lane = threadIdx.x & 63;
    const int col16 = lane & 15, quad = lane >> 4;
    const int g = wave >> 2;                         // gate 0..2
    const int s = wave & 3;                          // col-slice of 32

    // persistent B fragments: rows (g*128 + s*32 + ct*16 + col16), k = kt*32+quad*8
    f16x8 b[2][8];
#pragma unroll
    for (int ct = 0; ct < 2; ct++) {
        const _Float16* bp = Bc + (((size_t)(g * 128 + s * 32 + ct * 16 + col16)) << 8) + quad * 8;
#pragma unroll
        for (int kt = 0; kt < 8; kt++) b[ct][kt] = *(const f16x8*)(bp + kt * 32);
    }

    const int olocal = (wave & 3) * 1024 + lane * 16;   // within-part byte offset
    const int oswl = olocal ^ (((olocal >> 8) & 7) << 4);
    const char* sbase = (wave < 4) ? (const char*)ah : (const char*)hh;

    const int abase = col16 * 256 + quad * 16;
    const int axor = (col16 & 7) << 4;

    auto STAGE = [&](int iter) {
        if (wave < 8) {
            int tt = blockIdx.x + iter * GRU_BLOCKS;
            if (tt >= GRU_TILES) tt = GRU_TILES - 1;  // clamp keeps vmcnt accounting uniform
            const char* gp = sbase + (size_t)tt * 4096 + oswl;
            char* lp = &Ast[iter & 3][wave * 1024];   // wave-uniform base; HW adds lane*16
            __builtin_amdgcn_global_load_lds(
                (const __attribute__((address_space(1))) void*)gp,
                (__attribute__((address_space(3))) void*)lp, 16, 0, 0);
        }
    };

    STAGE(0);
    STAGE(1);
    asm volatile("s_waitcnt vmcnt(1)" ::: "memory");
    __builtin_amdgcn_s_barrier();
    __builtin_amdgcn_sched_barrier(0);

    int it = 0;
    for (int tile = blockIdx.x; tile < GRU_TILES; tile += GRU_BLOCKS, ++it) {
        const int r0 = tile * 16;
        STAGE(it + 2);                               // 2-deep prefetch into ring slot

        const char* As = (const char*)Ast[it & 3];
        float* Xb = X[it & 1];

        f16x8 A[8];                                  // kt<4 = ah part, kt>=4 = hh part
#pragma unroll
        for (int kt = 0; kt < 8; kt++) {
            int off = ((kt & 4) << 10) + abase + (kt & 3) * 64;
            off ^= axor;                             // undo staging swizzle
            A[kt] = *(const f16x8*)(As + off);
        }

        f32x4 acc[2][2];                             // [khalf-set][ct]; g<2 uses set 0 only
#pragma unroll
        for (int u = 0; u < 2; u++)
#pragma unroll
            for (int ct = 0; ct < 2; ct++) acc[u][ct] = (f32x4){0.f, 0.f, 0.f, 0.f};
#pragma unroll
        for (int kt = 0; kt < 8; kt++) {
            const int set = (g == 2 && kt >= 4) ? 1 : 0;
#pragma unroll
            for (int ct = 0; ct < 2; ct++)
                acc[set][ct] = __builtin_amdgcn_mfma_f32_16x16x32_f16(
                    A[kt], b[ct][kt], acc[set][ct], 0, 0, 0);
        }

        // acc -> LDS exchange (double-buffered)
#pragma unroll
        for (int ct = 0; ct < 2; ct++) {
            const int cbase = s * 32 + ct * 16 + col16;
            if (g < 2) {
#pragma unroll
                for (int i = 0; i < 4; i++)
                    Xb[g * (16 * LSTRIDE) + (quad * 4 + i) * LSTRIDE + cbase] = acc[0][ct][i];
            } else {
#pragma unroll
                for (int i = 0; i < 4; i++) {
                    Xb[2 * (16 * LSTRIDE) + (quad * 4 + i) * LSTRIDE + cbase] = acc[0][ct][i];
                    Xb[3 * (16 * LSTRIDE) + (quad * 4 + i) * LSTRIDE + cbase] = acc[1][ct][i];
                }
            }
        }

        asm volatile("s_waitcnt vmcnt(1) lgkmcnt(0)" ::: "memory");
        __builtin_amdgcn_s_barrier();
        __builtin_amdgcn_sched_barrier(0);

        // epilogue: 2048 elems over 768 threads; hprev from staged hh in LDS
#pragma unroll
        for (int pazz = 0; pazz < 3; pazz++) {
            int e = threadIdx.x + pazz * 768;
            if (e < 2048) {
                int row = e >> 7, col = e & 127;
                float vr = Xb[0 * (16 * LSTRIDE) + row * LSTRIDE + col];
                float vz = Xb[1 * (16 * LSTRIDE) + row * LSTRIDE + col];
                float vin = Xb[2 * (16 * LSTRIDE) + row * LSTRIDE + col];
                float vhn = Xb[3 * (16 * LSTRIDE) + row * LSTRIDE + col];
                float r = sigmoid_fast(vr + b_ih[col] + b_hh[col]);
                float z = sigmoid_fast(vz + b_ih[128 + col] + b_hh[128 + col]);
                float nn = tanh_fast(vin + b_ih[256 + col] + r * (vhn + b_hh[256 + col]));
                int hoff = (4096 + row * 256 + col * 2) ^ ((row & 7) << 4);
                float hprev = (float)*(const _Float16*)(As + hoff);
                float hv = (1.f - z) * nn + z * hprev;
                size_t idx = ((size_t)(r0 + row) << 7) + col;
                hh_next[idx] = (_Float16)hv;
                if (out_f32) out_f32[idx] = hv;
            }
        }
    }
    asm volatile("s_waitcnt vmcnt(0)" ::: "memory"); // drain ring prefetch before endpgm
}

// ---------------- launch ----------------

extern "C" void kernel_launch(void* const* d_in, const int* in_sizes, int n_in,
                              void* d_out, int out_size, void* d_ws, size_t ws_size,
                              hipStream_t stream) {
    const float* h0    = (const float*)d_in[0];
    const int*   src   = (const int*)d_in[1];
    const int*   dst   = (const int*)d_in[2];
    const int*   ety   = (const int*)d_in[3];
    const float* W_lin = (const float*)d_in[4];
    const float* b_lin = (const float*)d_in[5];
    const float* w_ih  = (const float*)d_in[6];
    const float* w_hh  = (const float*)d_in[7];
    const float* b_ih  = (const float*)d_in[8];
    const float* b_hh  = (const float*)d_in[9];
    float* hout = (float*)d_out;

    char* p = (char*)d_ws;
    auto alloc = [&](size_t bytes) -> char* {
        char* r = p;
        p += (bytes + 255) & ~(size_t)255;
        return r;
    };
    _Float16* h_a    = (_Float16*)alloc((size_t)N_NODES * DF * 2);
    _Float16* h_b    = (_Float16*)alloc((size_t)N_NODES * DF * 2);
    _Float16* a_half = (_Float16*)alloc((size_t)N_NODES * DF * 2);
    _Float16* t_half = (_Float16*)alloc((size_t)N_ETYPES * N_NODES * DF * 2);
    _Float16* Wl_h   = (_Float16*)alloc((size_t)N_ETYPES * DF * DF * 2);
    _Float16* Bc     = (_Float16*)alloc((size_t)3 * DF * 2 * DF * 2);   // [384][256] f16
    int* deg       = (int*)alloc((size_t)N_NODES * 4);
    int* row_start = (int*)alloc((size_t)(N_NODES + 1) * 4);
    int* cursor    = (int*)alloc((size_t)N_NODES * 4);
    int* csr       = (int*)alloc((size_t)N_EDGES * 4);
    int* part      = (int*)alloc((size_t)SCAN_NB * 4);

    hipMemsetAsync(deg, 0, (size_t)N_NODES * 4, stream);
    k_cvt_w<<<384, 256, 0, stream>>>(W_lin, w_ih, w_hh, Wl_h, Bc);
    k_cvt_h<<<(N_NODES * DF / 4 + 255) / 256, 256, 0, stream>>>(h0, h_a, N_NODES * DF / 4);
    k_hist<<<(N_EDGES + 255) / 256, 256, 0, stream>>>(dst, deg, N_EDGES);
    k_part<<<SCAN_NB, 256, 0, stream>>>(deg, part, N_NODES);
    k_scan1<<<1, 256, 0, stream>>>(part, SCAN_NB);
    k_row<<<SCAN_NB, 256, 0, stream>>>(deg, part, row_start, cursor, N_NODES);
    k_fill<<<FILL_CHUNKS * 8, 256, 0, stream>>>(src, dst, ety, cursor, csr, N_EDGES);

    _Float16* hc = h_a;
    _Float16* hn = h_b;
    for (int s = 0; s < N_STEPS; s++) {
        k_lin<<<LIN_BLOCKS, 1024, 0, stream>>>(hc, Wl_h, b_lin, t_half, N_NODES);
        k_agg<<<N_NODES / 4, 256, 0, stream>>>(t_half, row_start, csr, a_half, N_NODES);
        float* of = (s == N_STEPS - 1) ? hout : nullptr;
        k_gru<<<GRU_BLOCKS, 768, 0, stream>>>(a_half, hc, Bc, b_ih, b_hh, hn, of);
        _Float16* tmp = hc; hc = hn; hn = tmp;
    }
}